// Round 8
// baseline (534.031 us; speedup 1.0000x reference)
//
#include <hip/hip_runtime.h>
#include <hip/hip_bf16.h>

typedef short short8 __attribute__((ext_vector_type(8)));
typedef float f32x4 __attribute__((ext_vector_type(4)));
typedef unsigned short u16;
typedef unsigned int u32;

__device__ __forceinline__ u16 bf16rne(float f) {
    u32 u = __float_as_uint(f);
    u32 r = (u + 0x7fffu + ((u >> 16) & 1u)) >> 16;
    return (u16)r;
}
__device__ __forceinline__ float bf2f(u16 s) {
    return __uint_as_float(((u32)s) << 16);
}

// LDS-only barrier: wave-sync + LDS visibility WITHOUT draining vmcnt, so
// scatter atomics and prefetch loads stay in flight across barriers.
__device__ __forceinline__ void ldsbar() {
    asm volatile("s_waitcnt lgkmcnt(0)" ::: "memory");
    __builtin_amdgcn_s_barrier();
    asm volatile("" ::: "memory");
}

// ---------------------------------------------------------------------------
// Weight swizzle into MFMA B-fragment order, bf16 (unchanged).
// ---------------------------------------------------------------------------
__device__ __forceinline__ void swz(const float* __restrict__ src,
                                    u16* __restrict__ dst, int K, int KT,
                                    int tid0, int stride) {
    int total = 4 * KT * 512;
    for (int i = tid0; i < total; i += stride) {
        int j = i & 7, lane = (i >> 3) & 63, g = i >> 9;
        int kt = g % KT;
        int k = kt * 32 + (lane >> 4) * 8 + j;
        int n = (g / KT) * 16 + (lane & 15);
        dst[i] = (k < K) ? bf16rne(src[k * 64 + n]) : (u16)0;
    }
}

// ---------------------------------------------------------------------------
// Fused prep_weights (blocks [0,40)) + hist2 (blocks [40,552)).
// ---------------------------------------------------------------------------
__global__ void prep_hist(
    const float* ev1, const float* ev2, const float* ec1, const float* ec2,
    const float* cg1, const float* cg2, const float* cf1, const float* cf2,
    const float* vg1, const float* vg2, const float* vf1, const float* vf2,
    const float* t1,
    u16* dev1, u16* dev2, u16* dec1, u16* dec2, u16* dcg1, u16* dcg2,
    u16* dcf1, u16* dcf2, u16* dvg1, u16* dvg2, u16* dvf1, u16* dvf2,
    u16* dt1,
    const int* __restrict__ ci, const int* __restrict__ vi, int ne, int nc,
    int* __restrict__ cnt, u32* __restrict__ ranks) {
    int b = blockIdx.x;
    if (b < 40) {
        int tid0 = b * blockDim.x + threadIdx.x;
        int st = 40 * blockDim.x;
        swz(ev1, dev1, 19, 1, tid0, st);
        swz(ev2, dev2, 64, 2, tid0, st);
        swz(ec1, dec1, 5, 1, tid0, st);
        swz(ec2, dec2, 64, 2, tid0, st);
        swz(cg1, dcg1, 129, 5, tid0, st);
        swz(cg2, dcg2, 64, 2, tid0, st);
        swz(cf1, dcf1, 128, 4, tid0, st);
        swz(cf2, dcf2, 64, 2, tid0, st);
        swz(vg1, dvg1, 129, 5, tid0, st);
        swz(vg2, dvg2, 64, 2, tid0, st);
        swz(vf1, dvf1, 128, 4, tid0, st);
        swz(vf2, dvf2, 64, 2, tid0, st);
        swz(t1, dt1, 64, 2, tid0, st);
    } else {
        int i = (b - 40) * blockDim.x + threadIdx.x;
        int st = 512 * blockDim.x;
        for (; i < ne; i += st) {
            int rc = atomicAdd(&cnt[ci[i]], 1);
            int rv = atomicAdd(&cnt[nc + vi[i]], 1);
            ranks[i] = ((u32)rc & 0xffffu) | ((u32)rv << 16);
        }
    }
}

// ---------------------------------------------------------------------------
// scan_part + last-block bsum scan (device-scope acquire/release).
// ---------------------------------------------------------------------------
#define SCAN_CHUNK 4096

__global__ void scan_part_bsum(const int* __restrict__ cnt, int nd,
                               int* __restrict__ bsum, int nb,
                               int* __restrict__ done) {
    __shared__ int sred[256];
    int b = blockIdx.x, t = threadIdx.x;
    int base = b * SCAN_CHUNK + t * 16;
    int s = 0;
#pragma unroll
    for (int j = 0; j < 16; j++) {
        int i = base + j;
        if (i < nd) s += cnt[i];
    }
    sred[t] = s;
    __syncthreads();
    for (int o = 128; o > 0; o >>= 1) {
        if (t < o) sred[t] += sred[t + o];
        __syncthreads();
    }
    if (t == 0) {
        __hip_atomic_store(&bsum[b], sred[0], __ATOMIC_RELEASE,
                           __HIP_MEMORY_SCOPE_AGENT);
        int prev = __hip_atomic_fetch_add(done, 1, __ATOMIC_ACQ_REL,
                                          __HIP_MEMORY_SCOPE_AGENT);
        if (prev == nb - 1) {
            int run = 0;
            for (int i = 0; i < nb; i++) {
                int vv = __hip_atomic_load(&bsum[i], __ATOMIC_ACQUIRE,
                                           __HIP_MEMORY_SCOPE_AGENT);
                __hip_atomic_store(&bsum[i], run, __ATOMIC_RELAXED,
                                   __HIP_MEMORY_SCOPE_AGENT);
                run += vv;
            }
        }
    }
}

__global__ void scan_final(const int* __restrict__ cnt, int nd,
                           const int* __restrict__ bsum,
                           int* __restrict__ basep) {
    __shared__ int sa[256];
    int b = blockIdx.x, t = threadIdx.x;
    int base = b * SCAN_CHUNK + t * 16;
    int loc[16];
    int s = 0;
#pragma unroll
    for (int j = 0; j < 16; j++) {
        int i = base + j;
        int v = (i < nd) ? cnt[i] : 0;
        loc[j] = s;
        s += v;
    }
    sa[t] = s;
    __syncthreads();
    int inc = s;
    for (int o = 1; o < 256; o <<= 1) {
        int v = (t >= o) ? sa[t - o] : 0;
        __syncthreads();
        sa[t] += v;
        __syncthreads();
    }
    int off = bsum[b] + sa[t] - inc;
#pragma unroll
    for (int j = 0; j < 16; j++) {
        int i = base + j;
        if (i < nd) basep[i] = off + loc[j];
    }
}

// ---------------------------------------------------------------------------
// Generic MFMA layer (unchanged).
// ---------------------------------------------------------------------------
template <int KT, int SA>
__device__ __forceinline__ void mfma_layer(const u16* __restrict__ Asrc,
                                           const short8* wf, float bv,
                                           u16* __restrict__ Hdst,
                                           int l15, int lq, int w) {
#pragma unroll
    for (int mt = 0; mt < 4; mt++) {
        f32x4 acc = {0.f, 0.f, 0.f, 0.f};
#pragma unroll
        for (int kt = 0; kt < KT; kt++) {
            short8 a = *(const short8*)(Asrc + (mt * 16 + l15) * SA + kt * 32 + lq * 8);
            acc = __builtin_amdgcn_mfma_f32_16x16x32_bf16(a, wf[kt], acc, 0, 0, 0);
        }
#pragma unroll
        for (int r = 0; r < 4; r++)
            Hdst[(mt * 16 + lq * 4 + r) * 72 + w * 16 + l15] =
                bf16rne(fmaxf(acc[r] + bv, 0.f));
    }
}

// ---------------------------------------------------------------------------
// Input node MLP body (device fn on a shared smem arena).
// ---------------------------------------------------------------------------
template <int KIN>
__device__ __forceinline__ void mlp_in_body(
    const float* __restrict__ x, int n_nodes,
    const u16* __restrict__ w1s, const float* __restrict__ b1,
    const u16* __restrict__ w2s, const float* __restrict__ b2,
    u16* __restrict__ outbf, int blkid, u16* __restrict__ smem) {
    u16* A = smem;                 // 64*40
    u16* H1 = smem + 64 * 40;      // 64*72
    u16* H2 = H1 + 64 * 72;        // 64*72
    int tid = threadIdx.x, l = tid & 63, w = tid >> 6;
    int l15 = l & 15, lq = l >> 4;
    int blk0 = blkid * 64;
    const int PW = 40 - KIN;
    for (int i = tid; i < 64 * PW; i += 256) {
        int r = i / PW, cc = KIN + (i - r * PW);
        A[r * 40 + cc] = 0;
    }
    for (int i = tid; i < 64 * KIN; i += 256) {
        int r = i / KIN, k = i - r * KIN;
        int gn = blk0 + r; if (gn >= n_nodes) gn = n_nodes - 1;
        A[r * 40 + k] = bf16rne(x[(size_t)gn * KIN + k]);
    }
    short8 w1f[1], w2f[2];
    w1f[0] = *(const short8*)(w1s + ((w * 1 + 0) * 64 + l) * 8);
#pragma unroll
    for (int kt = 0; kt < 2; kt++)
        w2f[kt] = *(const short8*)(w2s + ((w * 2 + kt) * 64 + l) * 8);
    float b1v = b1[w * 16 + l15], b2v = b2[w * 16 + l15];
    ldsbar();
    mfma_layer<1, 40>(A, w1f, b1v, H1, l15, lq, w);
    ldsbar();
    mfma_layer<2, 72>(H1, w2f, b2v, H2, l15, lq, w);
    ldsbar();
    for (int i = tid; i < 512; i += 256) {
        int r = i >> 3, c = i & 7;
        if (blk0 + r < n_nodes)
            *(uint4*)(outbf + (size_t)(blk0 + r) * 64 + c * 8) =
                *(const uint4*)(H2 + r * 72 + c * 8);
    }
}

// ---------------------------------------------------------------------------
// Mega kernel: se-scatter (blocks [0,512)) || ds-expansion (64 blocks,
// sequential fills -- dst needs NO scatter since ranges are contiguous) ||
// mlp_in v || mlp_in c || zero agg_c+agg_v (last 256 blocks).
// ---------------------------------------------------------------------------
#define MEGA_SC 512
#define MEGA_EX 64
#define MEGA_ZB 256

__global__ __launch_bounds__(256, 6) void mega(
    const int* __restrict__ ci, const int* __restrict__ vi,
    const float* __restrict__ ev, const u32* __restrict__ ranks,
    int ne, int nc, int nv, const int* __restrict__ basep,
    const int* __restrict__ cnt,
    int* __restrict__ dsarr, int2* __restrict__ searr,
    const float* __restrict__ vx, const u16* __restrict__ ev1s,
    const float* __restrict__ ev_b1, const u16* __restrict__ ev2s,
    const float* __restrict__ ev_b2, u16* __restrict__ v1bf,
    const float* __restrict__ cx, const u16* __restrict__ ec1s,
    const float* __restrict__ ec_b1, const u16* __restrict__ ec2s,
    const float* __restrict__ ec_b2, u16* __restrict__ c1bf,
    float* __restrict__ agg_c, float* __restrict__ agg_v) {
    __shared__ __align__(16) u16 smem[64 * 40 + 2 * 64 * 72];
    int b = blockIdx.x;
    int nb_v = (nv + 63) >> 6;
    int nb_c = (nc + 63) >> 6;
    if (b < MEGA_SC) {
        // scatter {src, ev} only (8 B/entry)
        int i = b * 256 + threadIdx.x;
        int st = MEGA_SC * 256;
        for (; i < ne; i += st) {
            int cd = ci[i], vd = vi[i];
            u32 rk = ranks[i];
            int eb = __float_as_int(ev[i]);
            int pc = basep[cd] + (int)(rk & 0xffffu);
            int pv = basep[nc + vd] + (int)(rk >> 16);
            searr[pc] = make_int2(vd, eb);
            searr[pv] = make_int2(cd, eb);
        }
    } else if (b < MEGA_SC + MEGA_EX) {
        // ds expansion: dest d occupies [basep[d], basep[d]+cnt[d])
        int t = (b - MEGA_SC) * 256 + threadIdx.x;
        int stp = MEGA_EX * 256;
        int nd = nc + nv;
        for (int d = t; d < nd; d += stp) {
            int p0 = basep[d];
            int n = cnt[d];
            int val = (d < nc) ? d : d - nc;
            for (int p = p0; p < p0 + n; p++) dsarr[p] = val;
        }
    } else if (b < MEGA_SC + MEGA_EX + nb_v) {
        mlp_in_body<19>(vx, nv, ev1s, ev_b1, ev2s, ev_b2, v1bf,
                        b - MEGA_SC - MEGA_EX, smem);
    } else if (b < MEGA_SC + MEGA_EX + nb_v + nb_c) {
        mlp_in_body<5>(cx, nc, ec1s, ec_b1, ec2s, ec_b2, c1bf,
                       b - MEGA_SC - MEGA_EX - nb_v, smem);
    } else {
        int zb = b - MEGA_SC - MEGA_EX - nb_v - nb_c;    // 0..MEGA_ZB-1
        size_t nct = (size_t)nc * 64;
        size_t total = nct + (size_t)nv * 64;
        float4 z = {0.f, 0.f, 0.f, 0.f};
        size_t i = ((size_t)zb * 256 + threadIdx.x) * 4;
        size_t stp = (size_t)MEGA_ZB * 256 * 4;
        for (; i < total; i += stp) {
            if (i < nct) *(float4*)(agg_c + i) = z;
            else         *(float4*)(agg_v + (i - nct)) = z;
        }
    }
}

// ---------------------------------------------------------------------------
// f-MLP staging (unchanged).
// ---------------------------------------------------------------------------
__device__ __forceinline__ void stage_concat_res(
    const u16* __restrict__ ubf, const float* __restrict__ agg,
    int blk0, int n_nodes, u16* __restrict__ A, int tid) {
    for (int i = tid; i < 64 * 24; i += 256) {
        int nd = i / 24, c = i - nd * 24;
        int gn = blk0 + nd; if (gn >= n_nodes) gn = n_nodes - 1;
        if (c < 8) {
            *(uint4*)(A + nd * 200 + c * 8) =
                *(const uint4*)(ubf + (size_t)gn * 64 + c * 8);
        } else {
            int q = c - 8;
            float4 av = *(const float4*)(agg + (size_t)gn * 64 + q * 4);
            u16 h0 = bf16rne(av.x), h1 = bf16rne(av.y);
            u16 h2 = bf16rne(av.z), h3 = bf16rne(av.w);
            uint2 hi;
            hi.x = (u32)h0 | ((u32)h1 << 16);
            hi.y = (u32)h2 | ((u32)h3 << 16);
            *(uint2*)(A + nd * 200 + 64 + q * 4) = hi;
            uint2 rs;
            rs.x = (u32)bf16rne(av.x - bf2f(h0)) | ((u32)bf16rne(av.y - bf2f(h1)) << 16);
            rs.y = (u32)bf16rne(av.z - bf2f(h2)) | ((u32)bf16rne(av.w - bf2f(h3)) << 16);
            *(uint2*)(A + nd * 200 + 128 + q * 4) = rs;
        }
    }
}

// ---------------------------------------------------------------------------
// c-side f-MLP (unchanged).
// ---------------------------------------------------------------------------
__global__ __launch_bounds__(256, 4) void node_mlp_f(
    const u16* __restrict__ ubf, const float* __restrict__ agg, int n_nodes,
    const u16* __restrict__ w1s, const float* __restrict__ b1,
    const u16* __restrict__ w2s, const float* __restrict__ b2,
    u16* __restrict__ outbf) {
    __shared__ __align__(16) u16 A[64 * 200];
    __shared__ __align__(16) u16 H1[64 * 72];
    int tid = threadIdx.x, l = tid & 63, w = tid >> 6;
    int l15 = l & 15, lq = l >> 4;
    int blk0 = blockIdx.x * 64;
    stage_concat_res(ubf, agg, blk0, n_nodes, A, tid);
    short8 w1f[6], w2f[2];
#pragma unroll
    for (int kt = 0; kt < 4; kt++)
        w1f[kt] = *(const short8*)(w1s + ((w * 4 + kt) * 64 + l) * 8);
    w1f[4] = w1f[2];
    w1f[5] = w1f[3];
#pragma unroll
    for (int kt = 0; kt < 2; kt++)
        w2f[kt] = *(const short8*)(w2s + ((w * 2 + kt) * 64 + l) * 8);
    float b1v = b1[w * 16 + l15], b2v = b2[w * 16 + l15];
    ldsbar();
    mfma_layer<6, 200>(A, w1f, b1v, H1, l15, lq, w);
    ldsbar();
    mfma_layer<2, 72>(H1, w2f, b2v, A, l15, lq, w);
    ldsbar();
    for (int i = tid; i < 512; i += 256) {
        int r = i >> 3, c = i & 7;
        if (blk0 + r < n_nodes)
            *(uint4*)(outbf + (size_t)(blk0 + r) * 64 + c * 8) =
                *(const uint4*)(A + r * 72 + c * 8);
    }
}

// ---------------------------------------------------------------------------
// v-side f-MLP + tail (unchanged).
// ---------------------------------------------------------------------------
__global__ __launch_bounds__(256, 3) void node_mlp_vf_tail(
    const u16* __restrict__ vbf, const float* __restrict__ agg, int n_nodes,
    const u16* __restrict__ w1s, const float* __restrict__ b1,
    const u16* __restrict__ w2s, const float* __restrict__ b2,
    const u16* __restrict__ t1s, const float* __restrict__ tb1,
    const float* __restrict__ tw2, const float* __restrict__ tb2,
    float* __restrict__ out) {
    __shared__ __align__(16) char smem[64 * 200 * 2 + 2 * 64 * 72 * 2];
    u16* A = (u16*)smem;
    float* XF = (float*)smem;
    u16* H1 = (u16*)(smem + 25600);
    u16* H2 = (u16*)(smem + 25600 + 9216);
    int tid = threadIdx.x, l = tid & 63, w = tid >> 6;
    int l15 = l & 15, lq = l >> 4;
    int blk0 = blockIdx.x * 64;
    stage_concat_res(vbf, agg, blk0, n_nodes, A, tid);
    short8 w1f[6], w2f[2], t1f[2];
#pragma unroll
    for (int kt = 0; kt < 4; kt++)
        w1f[kt] = *(const short8*)(w1s + ((w * 4 + kt) * 64 + l) * 8);
    w1f[4] = w1f[2];
    w1f[5] = w1f[3];
#pragma unroll
    for (int kt = 0; kt < 2; kt++) {
        w2f[kt] = *(const short8*)(w2s + ((w * 2 + kt) * 64 + l) * 8);
        t1f[kt] = *(const short8*)(t1s + ((w * 2 + kt) * 64 + l) * 8);
    }
    float b1v = b1[w * 16 + l15], b2v = b2[w * 16 + l15];
    float tb1v = tb1[w * 16 + l15];
    ldsbar();
    mfma_layer<6, 200>(A, w1f, b1v, H1, l15, lq, w);
    ldsbar();
    mfma_layer<2, 72>(H1, w2f, b2v, H2, l15, lq, w);
    ldsbar();
#pragma unroll
    for (int mt = 0; mt < 4; mt++) {
        f32x4 acc = {0.f, 0.f, 0.f, 0.f};
#pragma unroll
        for (int kt = 0; kt < 2; kt++) {
            short8 a = *(const short8*)(H2 + (mt * 16 + l15) * 72 + kt * 32 + lq * 8);
            acc = __builtin_amdgcn_mfma_f32_16x16x32_bf16(a, t1f[kt], acc, 0, 0, 0);
        }
#pragma unroll
        for (int r = 0; r < 4; r++)
            XF[(mt * 16 + lq * 4 + r) * 65 + w * 16 + l15] =
                fmaxf(acc[r] + tb1v, 0.f);
    }
    ldsbar();
    float s0 = tb2[2 * w], s1 = tb2[2 * w + 1];
    for (int k = 0; k < 64; k++) {
        float xk = XF[l * 65 + k];
        float2 wp = *(const float2*)(tw2 + k * 8 + 2 * w);
        s0 = fmaf(xk, wp.x, s0);
        s1 = fmaf(xk, wp.y, s1);
    }
    if (blk0 + l < n_nodes) {
        float2 r;
        r.x = 1.f / (1.f + __expf(-s0));
        r.y = 1.f / (1.f + __expf(-s1));
        *(float2*)(out + (size_t)(blk0 + l) * 8 + 2 * w) = r;
    }
}

// ---------------------------------------------------------------------------
// Edge conv: R7's proven structure; edge stream split into ds[] (dst) +
// se[] {src, ev}. Index-fetch paths adapted; gather/MFMA/seg-reduce/atomic
// emission byte-identical.
// ---------------------------------------------------------------------------
#define AROW 168
#define HROW 72

__global__ __launch_bounds__(256, 5) void edge_conv(
    const u16* __restrict__ u_feat, const u16* __restrict__ v_feat,
    const int* __restrict__ dsp,    // sorted dst ids (side-local)
    const int2* __restrict__ sep,   // matching {src, ev_bits}
    const u16* __restrict__ w1s, const u16* __restrict__ w2s,
    const float* __restrict__ b1, const float* __restrict__ b2,
    float* __restrict__ agg, int n_tiles) {
    __shared__ __align__(16) u16 A[64 * AROW];   // staging; later G (f32) overlay
    __shared__ __align__(16) u16 Hs[64 * HROW];
    __shared__ int Didx[64];

    int tid = threadIdx.x;
    int lane = tid & 63;
    int w = tid >> 6;
    int l15 = lane & 15, lq = lane >> 4;
    int cch = tid & 15, e0 = tid >> 4;

    for (int i = tid; i < 64 * (AROW - 129); i += 256) {
        int r = i / (AROW - 129);
        int cc = 129 + (i - r * (AROW - 129));
        A[r * AROW + cc] = 0;
    }

    short8 w1f[5], w2f[2];
#pragma unroll
    for (int kt = 0; kt < 5; kt++)
        w1f[kt] = *(const short8*)(w1s + ((w * 5 + kt) * 64 + lane) * 8);
#pragma unroll
    for (int kt = 0; kt < 2; kt++)
        w2f[kt] = *(const short8*)(w2s + ((w * 2 + kt) * 64 + lane) * 8);
    float b1v = b1[w * 16 + l15];
    float b2v = b2[w * 16 + l15];

    const bool fsel = (cch < 8);
    const u16* fbase = fsel ? u_feat : v_feat;
    const int gcol = fsel ? cch * 8 : 64 + (cch - 8) * 8;
    const int coff = (cch & 7) * 8;

    const int G = gridDim.x;
    int tile = (int)blockIdx.x;

    uint4 st[4];   // staged features for current tile (loaded 1 iter ahead)
    u32 evb[4];    // e_val bits, current tile
    int pidx[4];   // gather index for NEXT tile (loaded 2 iters ahead)
    u32 pev[4];    // e_val bits for NEXT tile
    int didx_c = 0, didx_n = 0;

    if (tile < n_tiles) {
#pragma unroll
        for (int t = 0; t < 4; t++) {
            int ge = tile * 64 + e0 + t * 16;
            int ix;
            if (fsel) {
                ix = dsp[ge];
                if (cch == 0) evb[t] = (u32)sep[ge].y;
            } else {
                int2 s = sep[ge];
                ix = s.x;
                evb[t] = (u32)s.y;
            }
            st[t] = *(const uint4*)(fbase + (size_t)ix * 64 + coff);
        }
        if (tid < 64) didx_c = dsp[tile * 64 + tid];
        int ntp = tile + G;
        if (ntp < n_tiles) {
#pragma unroll
            for (int t = 0; t < 4; t++) {
                int ge = ntp * 64 + e0 + t * 16;
                if (fsel) {
                    pidx[t] = dsp[ge];
                    if (cch == 0) pev[t] = (u32)sep[ge].y;
                } else {
                    int2 s = sep[ge];
                    pidx[t] = s.x;
                    pev[t] = (u32)s.y;
                }
            }
        }
    }

    for (; tile < n_tiles; tile += G) {
        ldsbar();  // B0: prev seg-reduce reads of G done before commit writes
#pragma unroll
        for (int t = 0; t < 4; t++) {
            int e = e0 + t * 16;
            *(uint4*)(&A[e * AROW + gcol]) = st[t];
            if (cch == 0) A[e * AROW + 128] = bf16rne(__uint_as_float(evb[t]));
        }
        // issue next tile's gathers (indices already in regs) and the
        // tile-after-next's index loads; all overlap B1+L1+B2+L2
        int nt = tile + G;
        if (nt < n_tiles) {
#pragma unroll
            for (int t = 0; t < 4; t++) {
                st[t] = *(const uint4*)(fbase + (size_t)pidx[t] * 64 + coff);
                evb[t] = pev[t];
            }
            if (tid < 64) didx_n = dsp[nt * 64 + tid];
            int nt2 = nt + G;
            if (nt2 < n_tiles) {
#pragma unroll
                for (int t = 0; t < 4; t++) {
                    int ge = nt2 * 64 + e0 + t * 16;
                    if (fsel) {
                        pidx[t] = dsp[ge];
                        if (cch == 0) pev[t] = (u32)sep[ge].y;
                    } else {
                        int2 s = sep[ge];
                        pidx[t] = s.x;
                        pev[t] = (u32)s.y;
                    }
                }
            }
        }
        ldsbar();  // B1: A staged (LDS only; atomics/prefetch stay in flight)

#pragma unroll
        for (int mt = 0; mt < 4; mt++) {
            short8 a1[5];
#pragma unroll
            for (int kt = 0; kt < 5; kt++)
                a1[kt] = *(const short8*)(&A[(mt * 16 + l15) * AROW + kt * 32 + lq * 8]);
            f32x4 acc = {0.f, 0.f, 0.f, 0.f};
#pragma unroll
            for (int kt = 0; kt < 5; kt++)
                acc = __builtin_amdgcn_mfma_f32_16x16x32_bf16(a1[kt], w1f[kt], acc, 0, 0, 0);
#pragma unroll
            for (int r = 0; r < 4; r++) {
                float hv = fmaxf(acc[r] + b1v, 0.f);
                Hs[(mt * 16 + lq * 4 + r) * HROW + w * 16 + l15] = bf16rne(hv);
            }
        }
        ldsbar();  // B2: Hs ready; A reads done -> A region free for G

        float* Gf = (float*)A;  // row stride 84 floats; cols 0..63 used
#pragma unroll
        for (int mt = 0; mt < 4; mt++) {
            short8 a2[2];
#pragma unroll
            for (int kt = 0; kt < 2; kt++)
                a2[kt] = *(const short8*)(&Hs[(mt * 16 + l15) * HROW + kt * 32 + lq * 8]);
            f32x4 acc = {0.f, 0.f, 0.f, 0.f};
#pragma unroll
            for (int kt = 0; kt < 2; kt++)
                acc = __builtin_amdgcn_mfma_f32_16x16x32_bf16(a2[kt], w2f[kt], acc, 0, 0, 0);
#pragma unroll
            for (int r = 0; r < 4; r++)
                Gf[(mt * 16 + lq * 4 + r) * 84 + w * 16 + l15] =
                    fmaxf(acc[r] + b2v, 0.f);
        }
        if (tid < 64) Didx[tid] = didx_c;
        ldsbar();  // B3: G + Didx ready

        {
            int col = tid & 63, rg = tid >> 6;
            int r0 = rg * 16;
            int dcur = Didx[r0];
            float s = Gf[r0 * 84 + col];
#pragma unroll
            for (int r = 1; r < 16; r++) {
                int d = Didx[r0 + r];
                float g = Gf[(r0 + r) * 84 + col];
                if (d != dcur) {
                    __hip_atomic_fetch_add(&agg[(size_t)dcur * 64 + col], s,
                                           __ATOMIC_RELAXED, __HIP_MEMORY_SCOPE_AGENT);
                    dcur = d;
                    s = g;
                } else {
                    s += g;
                }
            }
            __hip_atomic_fetch_add(&agg[(size_t)dcur * 64 + col], s,
                                   __ATOMIC_RELAXED, __HIP_MEMORY_SCOPE_AGENT);
        }
        didx_c = didx_n;
    }
}

extern "C" void kernel_launch(void* const* d_in, const int* in_sizes, int n_in,
                              void* d_out, int out_size, void* d_ws, size_t ws_size,
                              hipStream_t stream) {
    const float* v        = (const float*)d_in[0];
    const float* c        = (const float*)d_in[1];
    const int*   cons_idx = (const int*)d_in[2];
    const int*   var_idx  = (const int*)d_in[3];
    const float* e_val    = (const float*)d_in[4];
    const float* ev_w1 = (const float*)d_in[5],  *ev_b1 = (const float*)d_in[6];
    const float* ev_w2 = (const float*)d_in[7],  *ev_b2 = (const float*)d_in[8];
    const float* ec_w1 = (const float*)d_in[9],  *ec_b1 = (const float*)d_in[10];
    const float* ec_w2 = (const float*)d_in[11], *ec_b2 = (const float*)d_in[12];
    const float* cg_w1 = (const float*)d_in[13], *cg_b1 = (const float*)d_in[14];
    const float* cg_w2 = (const float*)d_in[15], *cg_b2 = (const float*)d_in[16];
    const float* cf_w1 = (const float*)d_in[17], *cf_b1 = (const float*)d_in[18];
    const float* cf_w2 = (const float*)d_in[19], *cf_b2 = (const float*)d_in[20];
    const float* vg_w1 = (const float*)d_in[21], *vg_b1 = (const float*)d_in[22];
    const float* vg_w2 = (const float*)d_in[23], *vg_b2 = (const float*)d_in[24];
    const float* vf_w1 = (const float*)d_in[25], *vf_b1 = (const float*)d_in[26];
    const float* vf_w2 = (const float*)d_in[27], *vf_b2 = (const float*)d_in[28];
    const float* t_w1  = (const float*)d_in[29], *t_b1  = (const float*)d_in[30];
    const float* t_w2  = (const float*)d_in[31], *t_b2  = (const float*)d_in[32];

    const int NV = in_sizes[0] / 19;
    const int NC = in_sizes[1] / 5;
    const int NE = in_sizes[4];

    char* ws = (char*)d_ws;
    size_t off = 0;
    u16* v1bf = (u16*)(ws + off); off += (size_t)NV * 64 * 2;
    u16* c1bf = (u16*)(ws + off); off += (size_t)NC * 64 * 2;
    u16* c2bf = (u16*)(ws + off); off += (size_t)NC * 64 * 2;
    float* agg_c = (float*)(ws + off); off += (size_t)NC * 64 * 4;
    float* agg_v = (float*)(ws + off); off += (size_t)NV * 64 * 4;
    u16* ev1s = (u16*)(ws + off); off += 2048 * 2;
    u16* ev2s = (u16*)(ws + off); off += 4096 * 2;
    u16* ec1s = (u16*)(ws + off); off += 2048 * 2;
    u16* ec2s = (u16*)(ws + off); off += 4096 * 2;
    u16* cg1s = (u16*)(ws + off); off += 10240 * 2;
    u16* cg2s = (u16*)(ws + off); off += 4096 * 2;
    u16* cf1s = (u16*)(ws + off); off += 8192 * 2;
    u16* cf2s = (u16*)(ws + off); off += 4096 * 2;
    u16* vg1s = (u16*)(ws + off); off += 10240 * 2;
    u16* vg2s = (u16*)(ws + off); off += 4096 * 2;
    u16* vf1s = (u16*)(ws + off); off += 8192 * 2;
    u16* vf2s = (u16*)(ws + off); off += 4096 * 2;
    u16* t1s  = (u16*)(ws + off); off += 4096 * 2;
    off = (off + 255) & ~(size_t)255;
    int* cnt    = (int*)(ws + off); off += (size_t)(NC + NV) * 4;
    int* done   = (int*)(ws + off); off += 4;          // contiguous after cnt
    off = (off + 255) & ~(size_t)255;
    int* basep  = (int*)(ws + off); off += (size_t)(NC + NV) * 4;
    int* bsum   = (int*)(ws + off); off += 64 * 4;
    off = (off + 255) & ~(size_t)255;
    u32* ranks  = (u32*)(ws + off); off += (size_t)NE * 4;
    off = (off + 255) & ~(size_t)255;
    int* dsarr  = (int*)(ws + off); off += (size_t)NE * 2 * 4;
    off = (off + 255) & ~(size_t)255;
    int2* searr = (int2*)(ws + off); off += (size_t)NE * 2 * 8;

    const int n_tiles = NE / 64;
    const int nd = NC + NV;
    const int nb = (nd + SCAN_CHUNK - 1) / SCAN_CHUNK;
    const int nb_v = (NV + 63) / 64;
    const int nb_c = (NC + 63) / 64;

    // zero cnt + done in one memset (contiguous)
    hipMemsetAsync(cnt, 0, (size_t)nd * 4 + 4, stream);

    // 1) prep_weights || hist2
    prep_hist<<<552, 256, 0, stream>>>(
        ev_w1, ev_w2, ec_w1, ec_w2, cg_w1, cg_w2, cf_w1, cf_w2,
        vg_w1, vg_w2, vf_w1, vf_w2, t_w1,
        ev1s, ev2s, ec1s, ec2s, cg1s, cg2s, cf1s, cf2s,
        vg1s, vg2s, vf1s, vf2s, t1s,
        cons_idx, var_idx, NE, NC, cnt, (u32*)ranks);

    // 2) scan (block partials + fused last-block bsum scan), then bases
    scan_part_bsum<<<nb, 256, 0, stream>>>(cnt, nd, bsum, nb, done);
    scan_final<<<nb, 256, 0, stream>>>(cnt, nd, bsum, basep);

    // 3) se-scatter || ds-expansion || mlp_in v || mlp_in c || zero aggs
    mega<<<MEGA_SC + MEGA_EX + nb_v + nb_c + MEGA_ZB, 256, 0, stream>>>(
        cons_idx, var_idx, e_val, ranks, NE, NC, NV, basep, cnt,
        dsarr, searr,
        v, ev1s, ev_b1, ev2s, ev_b2, v1bf,
        c, ec1s, ec_b1, ec2s, ec_b2, c1bf,
        agg_c, agg_v);

    // 4) c-side conv + f-MLP
    edge_conv<<<1280, 256, 0, stream>>>(c1bf, v1bf, dsarr, searr,
                                        cg1s, cg2s, cg_b1, cg_b2, agg_c, n_tiles);
    node_mlp_f<<<nb_c, 256, 0, stream>>>(
        c1bf, agg_c, NC, cf1s, cf_b1, cf2s, cf_b2, c2bf);

    // 5) v-side conv + f-MLP + tail
    edge_conv<<<1280, 256, 0, stream>>>(v1bf, c2bf, dsarr + NE, searr + NE,
                                        vg1s, vg2s, vg_b1, vg_b2, agg_v, n_tiles);
    node_mlp_vf_tail<<<nb_v, 256, 0, stream>>>(
        v1bf, agg_v, NV, vf1s, vf_b1, vf2s, vf_b2,
        t1s, t_b1, t_w2, t_b2, (float*)d_out);
}

// Round 9
// 483.951 us; speedup vs baseline: 1.1035x; 1.1035x over previous
//
#include <hip/hip_runtime.h>
#include <hip/hip_bf16.h>

typedef short short8 __attribute__((ext_vector_type(8)));
typedef float f32x4 __attribute__((ext_vector_type(4)));
typedef unsigned short u16;
typedef unsigned int u32;

__device__ __forceinline__ u16 bf16rne(float f) {
    u32 u = __float_as_uint(f);
    u32 r = (u + 0x7fffu + ((u >> 16) & 1u)) >> 16;
    return (u16)r;
}
__device__ __forceinline__ float bf2f(u16 s) {
    return __uint_as_float(((u32)s) << 16);
}

// LDS-only barrier: wave-sync + LDS visibility WITHOUT draining vmcnt.
__device__ __forceinline__ void ldsbar() {
    asm volatile("s_waitcnt lgkmcnt(0)" ::: "memory");
    __builtin_amdgcn_s_barrier();
    asm volatile("" ::: "memory");
}

// ---------------------------------------------------------------------------
// Weight swizzle into MFMA B-fragment order, bf16 (unchanged).
// ---------------------------------------------------------------------------
__device__ __forceinline__ void swz(const float* __restrict__ src,
                                    u16* __restrict__ dst, int K, int KT,
                                    int tid0, int stride) {
    int total = 4 * KT * 512;
    for (int i = tid0; i < total; i += stride) {
        int j = i & 7, lane = (i >> 3) & 63, g = i >> 9;
        int kt = g % KT;
        int k = kt * 32 + (lane >> 4) * 8 + j;
        int n = (g / KT) * 16 + (lane & 15);
        dst[i] = (k < K) ? bf16rne(src[k * 64 + n]) : (u16)0;
    }
}

// ---------------------------------------------------------------------------
// Fused prep_weights (blocks [0,40)) + hist2 (blocks [40,552)).
// ---------------------------------------------------------------------------
__global__ void prep_hist(
    const float* ev1, const float* ev2, const float* ec1, const float* ec2,
    const float* cg1, const float* cg2, const float* cf1, const float* cf2,
    const float* vg1, const float* vg2, const float* vf1, const float* vf2,
    const float* t1,
    u16* dev1, u16* dev2, u16* dec1, u16* dec2, u16* dcg1, u16* dcg2,
    u16* dcf1, u16* dcf2, u16* dvg1, u16* dvg2, u16* dvf1, u16* dvf2,
    u16* dt1,
    const int* __restrict__ ci, const int* __restrict__ vi, int ne, int nc,
    int* __restrict__ cnt, u32* __restrict__ ranks) {
    int b = blockIdx.x;
    if (b < 40) {
        int tid0 = b * blockDim.x + threadIdx.x;
        int st = 40 * blockDim.x;
        swz(ev1, dev1, 19, 1, tid0, st);
        swz(ev2, dev2, 64, 2, tid0, st);
        swz(ec1, dec1, 5, 1, tid0, st);
        swz(ec2, dec2, 64, 2, tid0, st);
        swz(cg1, dcg1, 129, 5, tid0, st);
        swz(cg2, dcg2, 64, 2, tid0, st);
        swz(cf1, dcf1, 128, 4, tid0, st);
        swz(cf2, dcf2, 64, 2, tid0, st);
        swz(vg1, dvg1, 129, 5, tid0, st);
        swz(vg2, dvg2, 64, 2, tid0, st);
        swz(vf1, dvf1, 128, 4, tid0, st);
        swz(vf2, dvf2, 64, 2, tid0, st);
        swz(t1, dt1, 64, 2, tid0, st);
    } else {
        int i = (b - 40) * blockDim.x + threadIdx.x;
        int st = 512 * blockDim.x;
        for (; i < ne; i += st) {
            int rc = atomicAdd(&cnt[ci[i]], 1);
            int rv = atomicAdd(&cnt[nc + vi[i]], 1);
            ranks[i] = ((u32)rc & 0xffffu) | ((u32)rv << 16);
        }
    }
}

// ---------------------------------------------------------------------------
// scan_part + last-block bsum scan (device-scope acquire/release).
// ---------------------------------------------------------------------------
#define SCAN_CHUNK 4096

__global__ void scan_part_bsum(const int* __restrict__ cnt, int nd,
                               int* __restrict__ bsum, int nb,
                               int* __restrict__ done) {
    __shared__ int sred[256];
    int b = blockIdx.x, t = threadIdx.x;
    int base = b * SCAN_CHUNK + t * 16;
    int s = 0;
#pragma unroll
    for (int j = 0; j < 16; j++) {
        int i = base + j;
        if (i < nd) s += cnt[i];
    }
    sred[t] = s;
    __syncthreads();
    for (int o = 128; o > 0; o >>= 1) {
        if (t < o) sred[t] += sred[t + o];
        __syncthreads();
    }
    if (t == 0) {
        __hip_atomic_store(&bsum[b], sred[0], __ATOMIC_RELEASE,
                           __HIP_MEMORY_SCOPE_AGENT);
        int prev = __hip_atomic_fetch_add(done, 1, __ATOMIC_ACQ_REL,
                                          __HIP_MEMORY_SCOPE_AGENT);
        if (prev == nb - 1) {
            int run = 0;
            for (int i = 0; i < nb; i++) {
                int vv = __hip_atomic_load(&bsum[i], __ATOMIC_ACQUIRE,
                                           __HIP_MEMORY_SCOPE_AGENT);
                __hip_atomic_store(&bsum[i], run, __ATOMIC_RELAXED,
                                   __HIP_MEMORY_SCOPE_AGENT);
                run += vv;
            }
        }
    }
}

__global__ void scan_final(const int* __restrict__ cnt, int nd,
                           const int* __restrict__ bsum,
                           int* __restrict__ basep) {
    __shared__ int sa[256];
    int b = blockIdx.x, t = threadIdx.x;
    int base = b * SCAN_CHUNK + t * 16;
    int loc[16];
    int s = 0;
#pragma unroll
    for (int j = 0; j < 16; j++) {
        int i = base + j;
        int v = (i < nd) ? cnt[i] : 0;
        loc[j] = s;
        s += v;
    }
    sa[t] = s;
    __syncthreads();
    int inc = s;
    for (int o = 1; o < 256; o <<= 1) {
        int v = (t >= o) ? sa[t - o] : 0;
        __syncthreads();
        sa[t] += v;
        __syncthreads();
    }
    int off = bsum[b] + sa[t] - inc;
#pragma unroll
    for (int j = 0; j < 16; j++) {
        int i = base + j;
        if (i < nd) basep[i] = off + loc[j];
    }
}

// ---------------------------------------------------------------------------
// Generic MFMA layer (bf16 out, unchanged).
// ---------------------------------------------------------------------------
template <int KT, int SA>
__device__ __forceinline__ void mfma_layer(const u16* __restrict__ Asrc,
                                           const short8* wf, float bv,
                                           u16* __restrict__ Hdst,
                                           int l15, int lq, int w) {
#pragma unroll
    for (int mt = 0; mt < 4; mt++) {
        f32x4 acc = {0.f, 0.f, 0.f, 0.f};
#pragma unroll
        for (int kt = 0; kt < KT; kt++) {
            short8 a = *(const short8*)(Asrc + (mt * 16 + l15) * SA + kt * 32 + lq * 8);
            acc = __builtin_amdgcn_mfma_f32_16x16x32_bf16(a, wf[kt], acc, 0, 0, 0);
        }
#pragma unroll
        for (int r = 0; r < 4; r++)
            Hdst[(mt * 16 + lq * 4 + r) * 72 + w * 16 + l15] =
                bf16rne(fmaxf(acc[r] + bv, 0.f));
    }
}

// ---------------------------------------------------------------------------
// Partial-product layer: A(bf16, stride 72) @ 2 fragments -> f32 global
// [node][64]. No bias, no relu (raw W1-half product for the conv).
// ---------------------------------------------------------------------------
__device__ __forceinline__ void mfma_pout(const u16* __restrict__ Asrc,
                                          const short8* pf,
                                          float* __restrict__ outp,
                                          int blk0, int n_nodes,
                                          int l15, int lq, int w) {
#pragma unroll
    for (int mt = 0; mt < 4; mt++) {
        f32x4 acc = {0.f, 0.f, 0.f, 0.f};
#pragma unroll
        for (int kt = 0; kt < 2; kt++) {
            short8 a = *(const short8*)(Asrc + (mt * 16 + l15) * 72 + kt * 32 + lq * 8);
            acc = __builtin_amdgcn_mfma_f32_16x16x32_bf16(a, pf[kt], acc, 0, 0, 0);
        }
#pragma unroll
        for (int r = 0; r < 4; r++) {
            int gn = blk0 + mt * 16 + lq * 4 + r;
            if (gn < n_nodes)
                outp[(size_t)gn * 64 + w * 16 + l15] = acc[r];
        }
    }
}

// ---------------------------------------------------------------------------
// Input node MLP body + optional W1-partial outputs (from 5-ktile arrays;
// ktoff=0 selects the dst half (rows 0:64), ktoff=2 the src half (64:128)).
// ---------------------------------------------------------------------------
template <int KIN>
__device__ __forceinline__ void mlp_in_body(
    const float* __restrict__ x, int n_nodes,
    const u16* __restrict__ w1s, const float* __restrict__ b1,
    const u16* __restrict__ w2s, const float* __restrict__ b2,
    u16* __restrict__ outbf, int blkid, u16* __restrict__ smem,
    const u16* __restrict__ paw, int pakt, float* __restrict__ paout,
    const u16* __restrict__ pbw, int pbkt, float* __restrict__ pbout) {
    u16* A = smem;                 // 64*40
    u16* H1 = smem + 64 * 40;      // 64*72
    u16* H2 = H1 + 64 * 72;        // 64*72
    int tid = threadIdx.x, l = tid & 63, w = tid >> 6;
    int l15 = l & 15, lq = l >> 4;
    int blk0 = blkid * 64;
    const int PW = 40 - KIN;
    for (int i = tid; i < 64 * PW; i += 256) {
        int r = i / PW, cc = KIN + (i - r * PW);
        A[r * 40 + cc] = 0;
    }
    for (int i = tid; i < 64 * KIN; i += 256) {
        int r = i / KIN, k = i - r * KIN;
        int gn = blk0 + r; if (gn >= n_nodes) gn = n_nodes - 1;
        A[r * 40 + k] = bf16rne(x[(size_t)gn * KIN + k]);
    }
    short8 w1f[1], w2f[2];
    w1f[0] = *(const short8*)(w1s + ((w * 1 + 0) * 64 + l) * 8);
#pragma unroll
    for (int kt = 0; kt < 2; kt++)
        w2f[kt] = *(const short8*)(w2s + ((w * 2 + kt) * 64 + l) * 8);
    float b1v = b1[w * 16 + l15], b2v = b2[w * 16 + l15];
    ldsbar();
    mfma_layer<1, 40>(A, w1f, b1v, H1, l15, lq, w);
    ldsbar();
    mfma_layer<2, 72>(H1, w2f, b2v, H2, l15, lq, w);
    ldsbar();
    for (int i = tid; i < 512; i += 256) {
        int r = i >> 3, c = i & 7;
        if (blk0 + r < n_nodes)
            *(uint4*)(outbf + (size_t)(blk0 + r) * 64 + c * 8) =
                *(const uint4*)(H2 + r * 72 + c * 8);
    }
    if (paout) {
        short8 pf[2];
        pf[0] = *(const short8*)(paw + ((w * 5 + pakt + 0) * 64 + l) * 8);
        pf[1] = *(const short8*)(paw + ((w * 5 + pakt + 1) * 64 + l) * 8);
        mfma_pout(H2, pf, paout, blk0, n_nodes, l15, lq, w);
    }
    if (pbout) {
        short8 pf[2];
        pf[0] = *(const short8*)(pbw + ((w * 5 + pbkt + 0) * 64 + l) * 8);
        pf[1] = *(const short8*)(pbw + ((w * 5 + pbkt + 1) * 64 + l) * 8);
        mfma_pout(H2, pf, pbout, blk0, n_nodes, l15, lq, w);
    }
}

// ---------------------------------------------------------------------------
// Mega kernel (R7 segments): epk-scatter || mlp_in v (+Pu_v,+Pv_v) ||
// mlp_in c (+Pu_c) || zero agg_c+agg_v.
// ---------------------------------------------------------------------------
#define MEGA_SC 512
#define MEGA_ZB 256

__global__ __launch_bounds__(256, 6) void mega(
    const int* __restrict__ ci, const int* __restrict__ vi,
    const float* __restrict__ ev, const u32* __restrict__ ranks,
    int ne, int nc, int nv, const int* __restrict__ basep,
    int4* __restrict__ epk,
    const float* __restrict__ vx, const u16* __restrict__ ev1s,
    const float* __restrict__ ev_b1, const u16* __restrict__ ev2s,
    const float* __restrict__ ev_b2, u16* __restrict__ v1bf,
    const float* __restrict__ cx, const u16* __restrict__ ec1s,
    const float* __restrict__ ec_b1, const u16* __restrict__ ec2s,
    const float* __restrict__ ec_b2, u16* __restrict__ c1bf,
    const u16* __restrict__ cg1s, const u16* __restrict__ vg1s,
    float* __restrict__ pu_v, float* __restrict__ pv_v,
    float* __restrict__ pu_c,
    float* __restrict__ agg_c, float* __restrict__ agg_v) {
    __shared__ __align__(16) u16 smem[64 * 40 + 2 * 64 * 72];
    int b = blockIdx.x;
    int nb_v = (nv + 63) >> 6;
    int nb_c = (nc + 63) >> 6;
    if (b < MEGA_SC) {
        int i = b * 256 + threadIdx.x;
        int st = MEGA_SC * 256;
        for (; i < ne; i += st) {
            int cd = ci[i], vd = vi[i];
            u32 rk = ranks[i];
            int eb = __float_as_int(ev[i]);
            int pc = basep[cd] + (int)(rk & 0xffffu);
            int pv = basep[nc + vd] + (int)(rk >> 16);
            epk[pc] = make_int4(cd, vd, eb, 0);
            epk[pv] = make_int4(vd, cd, eb, 0);
        }
    } else if (b < MEGA_SC + nb_v) {
        // v1 + Pu_v (vg dst half, kt 0) + Pv_v (cg src half, kt 2)
        mlp_in_body<19>(vx, nv, ev1s, ev_b1, ev2s, ev_b2, v1bf, b - MEGA_SC,
                        smem, vg1s, 0, pu_v, cg1s, 2, pv_v);
    } else if (b < MEGA_SC + nb_v + nb_c) {
        // c1 + Pu_c (cg dst half, kt 0)
        mlp_in_body<5>(cx, nc, ec1s, ec_b1, ec2s, ec_b2, c1bf,
                       b - MEGA_SC - nb_v, smem, cg1s, 0, pu_c,
                       (const u16*)0, 0, (float*)0);
    } else {
        int zb = b - MEGA_SC - nb_v - nb_c;          // 0..MEGA_ZB-1
        size_t nct = (size_t)nc * 64;
        size_t total = nct + (size_t)nv * 64;
        float4 z = {0.f, 0.f, 0.f, 0.f};
        size_t i = ((size_t)zb * 256 + threadIdx.x) * 4;
        size_t stp = (size_t)MEGA_ZB * 256 * 4;
        for (; i < total; i += stp) {
            if (i < nct) *(float4*)(agg_c + i) = z;
            else         *(float4*)(agg_v + (i - nct)) = z;
        }
    }
}

// ---------------------------------------------------------------------------
// f-MLP staging (unchanged).
// ---------------------------------------------------------------------------
__device__ __forceinline__ void stage_concat_res(
    const u16* __restrict__ ubf, const float* __restrict__ agg,
    int blk0, int n_nodes, u16* __restrict__ A, int tid) {
    for (int i = tid; i < 64 * 24; i += 256) {
        int nd = i / 24, c = i - nd * 24;
        int gn = blk0 + nd; if (gn >= n_nodes) gn = n_nodes - 1;
        if (c < 8) {
            *(uint4*)(A + nd * 200 + c * 8) =
                *(const uint4*)(ubf + (size_t)gn * 64 + c * 8);
        } else {
            int q = c - 8;
            float4 av = *(const float4*)(agg + (size_t)gn * 64 + q * 4);
            u16 h0 = bf16rne(av.x), h1 = bf16rne(av.y);
            u16 h2 = bf16rne(av.z), h3 = bf16rne(av.w);
            uint2 hi;
            hi.x = (u32)h0 | ((u32)h1 << 16);
            hi.y = (u32)h2 | ((u32)h3 << 16);
            *(uint2*)(A + nd * 200 + 64 + q * 4) = hi;
            uint2 rs;
            rs.x = (u32)bf16rne(av.x - bf2f(h0)) | ((u32)bf16rne(av.y - bf2f(h1)) << 16);
            rs.y = (u32)bf16rne(av.z - bf2f(h2)) | ((u32)bf16rne(av.w - bf2f(h3)) << 16);
            *(uint2*)(A + nd * 200 + 128 + q * 4) = rs;
        }
    }
}

// ---------------------------------------------------------------------------
// c-side f-MLP + Pv_c2 output (vg src half, kt 2) for the v-side conv.
// ---------------------------------------------------------------------------
__global__ __launch_bounds__(256, 4) void node_mlp_f(
    const u16* __restrict__ ubf, const float* __restrict__ agg, int n_nodes,
    const u16* __restrict__ w1s, const float* __restrict__ b1,
    const u16* __restrict__ w2s, const float* __restrict__ b2,
    const u16* __restrict__ vg1s, float* __restrict__ pv_out,
    u16* __restrict__ outbf) {
    __shared__ __align__(16) u16 A[64 * 200];
    __shared__ __align__(16) u16 H1[64 * 72];
    int tid = threadIdx.x, l = tid & 63, w = tid >> 6;
    int l15 = l & 15, lq = l >> 4;
    int blk0 = blockIdx.x * 64;
    stage_concat_res(ubf, agg, blk0, n_nodes, A, tid);
    short8 w1f[6], w2f[2];
#pragma unroll
    for (int kt = 0; kt < 4; kt++)
        w1f[kt] = *(const short8*)(w1s + ((w * 4 + kt) * 64 + l) * 8);
    w1f[4] = w1f[2];
    w1f[5] = w1f[3];
#pragma unroll
    for (int kt = 0; kt < 2; kt++)
        w2f[kt] = *(const short8*)(w2s + ((w * 2 + kt) * 64 + l) * 8);
    float b1v = b1[w * 16 + l15], b2v = b2[w * 16 + l15];
    ldsbar();
    mfma_layer<6, 200>(A, w1f, b1v, H1, l15, lq, w);
    ldsbar();
    mfma_layer<2, 72>(H1, w2f, b2v, A, l15, lq, w);   // A region dead: reuse (c2)
    ldsbar();
    for (int i = tid; i < 512; i += 256) {
        int r = i >> 3, c = i & 7;
        if (blk0 + r < n_nodes)
            *(uint4*)(outbf + (size_t)(blk0 + r) * 64 + c * 8) =
                *(const uint4*)(A + r * 72 + c * 8);
    }
    {
        short8 pf[2];
        pf[0] = *(const short8*)(vg1s + ((w * 5 + 2) * 64 + l) * 8);
        pf[1] = *(const short8*)(vg1s + ((w * 5 + 3) * 64 + l) * 8);
        mfma_pout(A, pf, pv_out, blk0, n_nodes, l15, lq, w);
    }
}

// ---------------------------------------------------------------------------
// v-side f-MLP + tail (unchanged).
// ---------------------------------------------------------------------------
__global__ __launch_bounds__(256, 3) void node_mlp_vf_tail(
    const u16* __restrict__ vbf, const float* __restrict__ agg, int n_nodes,
    const u16* __restrict__ w1s, const float* __restrict__ b1,
    const u16* __restrict__ w2s, const float* __restrict__ b2,
    const u16* __restrict__ t1s, const float* __restrict__ tb1,
    const float* __restrict__ tw2, const float* __restrict__ tb2,
    float* __restrict__ out) {
    __shared__ __align__(16) char smem[64 * 200 * 2 + 2 * 64 * 72 * 2];
    u16* A = (u16*)smem;
    float* XF = (float*)smem;
    u16* H1 = (u16*)(smem + 25600);
    u16* H2 = (u16*)(smem + 25600 + 9216);
    int tid = threadIdx.x, l = tid & 63, w = tid >> 6;
    int l15 = l & 15, lq = l >> 4;
    int blk0 = blockIdx.x * 64;
    stage_concat_res(vbf, agg, blk0, n_nodes, A, tid);
    short8 w1f[6], w2f[2], t1f[2];
#pragma unroll
    for (int kt = 0; kt < 4; kt++)
        w1f[kt] = *(const short8*)(w1s + ((w * 4 + kt) * 64 + l) * 8);
    w1f[4] = w1f[2];
    w1f[5] = w1f[3];
#pragma unroll
    for (int kt = 0; kt < 2; kt++) {
        w2f[kt] = *(const short8*)(w2s + ((w * 2 + kt) * 64 + l) * 8);
        t1f[kt] = *(const short8*)(t1s + ((w * 2 + kt) * 64 + l) * 8);
    }
    float b1v = b1[w * 16 + l15], b2v = b2[w * 16 + l15];
    float tb1v = tb1[w * 16 + l15];
    ldsbar();
    mfma_layer<6, 200>(A, w1f, b1v, H1, l15, lq, w);
    ldsbar();
    mfma_layer<2, 72>(H1, w2f, b2v, H2, l15, lq, w);
    ldsbar();
#pragma unroll
    for (int mt = 0; mt < 4; mt++) {
        f32x4 acc = {0.f, 0.f, 0.f, 0.f};
#pragma unroll
        for (int kt = 0; kt < 2; kt++) {
            short8 a = *(const short8*)(H2 + (mt * 16 + l15) * 72 + kt * 32 + lq * 8);
            acc = __builtin_amdgcn_mfma_f32_16x16x32_bf16(a, t1f[kt], acc, 0, 0, 0);
        }
#pragma unroll
        for (int r = 0; r < 4; r++)
            XF[(mt * 16 + lq * 4 + r) * 65 + w * 16 + l15] =
                fmaxf(acc[r] + tb1v, 0.f);
    }
    ldsbar();
    float s0 = tb2[2 * w], s1 = tb2[2 * w + 1];
    for (int k = 0; k < 64; k++) {
        float xk = XF[l * 65 + k];
        float2 wp = *(const float2*)(tw2 + k * 8 + 2 * w);
        s0 = fmaf(xk, wp.x, s0);
        s1 = fmaf(xk, wp.y, s1);
    }
    if (blk0 + l < n_nodes) {
        float2 r;
        r.x = 1.f / (1.f + __expf(-s0));
        r.y = 1.f / (1.f + __expf(-s1));
        *(float2*)(out + (size_t)(blk0 + l) * 8 + 2 * w) = r;
    }
}

// ---------------------------------------------------------------------------
// Edge conv, R9: W1-linearity decomposition. Per edge:
//   h1 = relu(Pu[dst] + Pv[src] + e*w1e + b1)   (VALU, f32)
// -> bf16 Hs -> B1 -> L2 MFMA (8/tile) -> Gf -> B2 -> seg-reduce.
// No L1 MFMA, no A tile, no u/v-feature gathers; 2 barriers/tile.
// Pv gather pipelined 1 tile ahead; epk indices 2 ahead. Didx double-
// buffered (staging overlaps prev seg-reduce).
// LDS = 9216(Hs) + 16896(Gf, stride 66) + 512(Didx[2]) = 26624 B.
// ---------------------------------------------------------------------------
#define HROW 72
#define GST 66

__global__ __launch_bounds__(256, 5) void edge_conv(
    const float* __restrict__ Pu,   // [ndst][64] f32 W1-dst partial
    const float* __restrict__ Pv,   // [nsrc][64] f32 W1-src partial
    const int4* __restrict__ epk,   // sorted packed edges {dst, src, ev, 0}
    const float* __restrict__ w1e,  // W1 row 128 (e column), 64 f32
    const float* __restrict__ b1,
    const u16* __restrict__ w2s, const float* __restrict__ b2,
    float* __restrict__ agg, int n_tiles) {
    __shared__ __align__(16) u16 Hs[64 * HROW];
    __shared__ __align__(16) float Gf[64 * GST];
    __shared__ int Didx[2][64];

    int tid = threadIdx.x;
    int lane = tid & 63;
    int w = tid >> 6;
    int l15 = lane & 15, lq = lane >> 4;
    int cch = tid & 15, e0 = tid >> 4;   // thread: edges e0+16t, cols cch*4..+4

    short8 w2f[2];
#pragma unroll
    for (int kt = 0; kt < 2; kt++)
        w2f[kt] = *(const short8*)(w2s + ((w * 2 + kt) * 64 + lane) * 8);
    float b2v = b2[w * 16 + l15];
    float4 w1e4 = *(const float4*)(w1e + cch * 4);
    float4 b14  = *(const float4*)(b1 + cch * 4);

    const int* epki = (const int*)epk;
    const int G = gridDim.x;
    int tile = (int)blockIdx.x;

    f32x4 pvc[4];          // Pv gather, current tile (prefetched 1 ahead)
    u32 evc[4];            // e_val bits, current tile
    int dstc[4];           // dst ids, current tile
    int ndst[4], nsrc[4];  // epk fields for NEXT tile (prefetched 2 ahead)
    u32 nev[4];
    int didx_c = 0, didx_n = 0;
    int par = 0;

    if (tile < n_tiles) {
#pragma unroll
        for (int t = 0; t < 4; t++) {
            int4 e = epk[tile * 64 + e0 + t * 16];
            pvc[t] = *(const f32x4*)(Pv + (size_t)e.y * 64 + cch * 4);
            evc[t] = (u32)e.z;
            dstc[t] = e.x;
        }
        if (tid < 64) didx_c = epki[(tile * 64 + tid) * 4];
        int ntp = tile + G;
        if (ntp < n_tiles) {
#pragma unroll
            for (int t = 0; t < 4; t++) {
                int4 e = epk[ntp * 64 + e0 + t * 16];
                ndst[t] = e.x; nsrc[t] = e.y; nev[t] = (u32)e.z;
            }
        }
    }

    for (; tile < n_tiles; tile += G) {
        // stage Hs: h1 = relu(Pu[dst] + Pv[src] + e*w1e + b1) -> bf16
#pragma unroll
        for (int t = 0; t < 4; t++) {
            int e = e0 + t * 16;
            f32x4 pu4 = *(const f32x4*)(Pu + (size_t)dstc[t] * 64 + cch * 4);
            float ev = __uint_as_float(evc[t]);
            float h0 = fmaxf(pvc[t][0] + pu4[0] + ev * w1e4.x + b14.x, 0.f);
            float h1 = fmaxf(pvc[t][1] + pu4[1] + ev * w1e4.y + b14.y, 0.f);
            float h2 = fmaxf(pvc[t][2] + pu4[2] + ev * w1e4.z + b14.z, 0.f);
            float h3 = fmaxf(pvc[t][3] + pu4[3] + ev * w1e4.w + b14.w, 0.f);
            uint2 pk;
            pk.x = (u32)bf16rne(h0) | ((u32)bf16rne(h1) << 16);
            pk.y = (u32)bf16rne(h2) | ((u32)bf16rne(h3) << 16);
            *(uint2*)(&Hs[e * HROW + cch * 4]) = pk;
        }
        if (tid < 64) Didx[par][tid] = didx_c;
        // pipeline: gather next tile's Pv (indices in regs), prefetch tile+2
        int nt = tile + G;
        if (nt < n_tiles) {
#pragma unroll
            for (int t = 0; t < 4; t++) {
                pvc[t] = *(const f32x4*)(Pv + (size_t)nsrc[t] * 64 + cch * 4);
                evc[t] = nev[t];
                dstc[t] = ndst[t];
            }
            if (tid < 64) didx_n = epki[(nt * 64 + tid) * 4];
            int nt2 = nt + G;
            if (nt2 < n_tiles) {
#pragma unroll
                for (int t = 0; t < 4; t++) {
                    int4 e = epk[nt2 * 64 + e0 + t * 16];
                    ndst[t] = e.x; nsrc[t] = e.y; nev[t] = (u32)e.z;
                }
            }
        }
        ldsbar();  // B1: Hs + Didx[par] ready; prev seg-reduce Gf reads done

        // L2 MFMA -> Gf (f32, stride 66)
#pragma unroll
        for (int mt = 0; mt < 4; mt++) {
            short8 a2[2];
#pragma unroll
            for (int kt = 0; kt < 2; kt++)
                a2[kt] = *(const short8*)(&Hs[(mt * 16 + l15) * HROW + kt * 32 + lq * 8]);
            f32x4 acc = {0.f, 0.f, 0.f, 0.f};
#pragma unroll
            for (int kt = 0; kt < 2; kt++)
                acc = __builtin_amdgcn_mfma_f32_16x16x32_bf16(a2[kt], w2f[kt], acc, 0, 0, 0);
#pragma unroll
            for (int r = 0; r < 4; r++)
                Gf[(mt * 16 + lq * 4 + r) * GST + w * 16 + l15] =
                    fmaxf(acc[r] + b2v, 0.f);
        }
        ldsbar();  // B2: Gf ready

        // segmented reduce (unchanged): thread t scans 16 rows of col t&63
        {
            int col = tid & 63, rg = tid >> 6;
            int r0 = rg * 16;
            int dcur = Didx[par][r0];
            float s = Gf[r0 * GST + col];
#pragma unroll
            for (int r = 1; r < 16; r++) {
                int d = Didx[par][r0 + r];
                float g = Gf[(r0 + r) * GST + col];
                if (d != dcur) {
                    __hip_atomic_fetch_add(&agg[(size_t)dcur * 64 + col], s,
                                           __ATOMIC_RELAXED, __HIP_MEMORY_SCOPE_AGENT);
                    dcur = d;
                    s = g;
                } else {
                    s += g;
                }
            }
            __hip_atomic_fetch_add(&agg[(size_t)dcur * 64 + col], s,
                                   __ATOMIC_RELAXED, __HIP_MEMORY_SCOPE_AGENT);
        }
        didx_c = didx_n;
        par ^= 1;
    }
}

extern "C" void kernel_launch(void* const* d_in, const int* in_sizes, int n_in,
                              void* d_out, int out_size, void* d_ws, size_t ws_size,
                              hipStream_t stream) {
    const float* v        = (const float*)d_in[0];
    const float* c        = (const float*)d_in[1];
    const int*   cons_idx = (const int*)d_in[2];
    const int*   var_idx  = (const int*)d_in[3];
    const float* e_val    = (const float*)d_in[4];
    const float* ev_w1 = (const float*)d_in[5],  *ev_b1 = (const float*)d_in[6];
    const float* ev_w2 = (const float*)d_in[7],  *ev_b2 = (const float*)d_in[8];
    const float* ec_w1 = (const float*)d_in[9],  *ec_b1 = (const float*)d_in[10];
    const float* ec_w2 = (const float*)d_in[11], *ec_b2 = (const float*)d_in[12];
    const float* cg_w1 = (const float*)d_in[13], *cg_b1 = (const float*)d_in[14];
    const float* cg_w2 = (const float*)d_in[15], *cg_b2 = (const float*)d_in[16];
    const float* cf_w1 = (const float*)d_in[17], *cf_b1 = (const float*)d_in[18];
    const float* cf_w2 = (const float*)d_in[19], *cf_b2 = (const float*)d_in[20];
    const float* vg_w1 = (const float*)d_in[21], *vg_b1 = (const float*)d_in[22];
    const float* vg_w2 = (const float*)d_in[23], *vg_b2 = (const float*)d_in[24];
    const float* vf_w1 = (const float*)d_in[25], *vf_b1 = (const float*)d_in[26];
    const float* vf_w2 = (const float*)d_in[27], *vf_b2 = (const float*)d_in[28];
    const float* t_w1  = (const float*)d_in[29], *t_b1  = (const float*)d_in[30];
    const float* t_w2  = (const float*)d_in[31], *t_b2  = (const float*)d_in[32];

    const int NV = in_sizes[0] / 19;
    const int NC = in_sizes[1] / 5;
    const int NE = in_sizes[4];

    char* ws = (char*)d_ws;
    size_t off = 0;
    u16* v1bf = (u16*)(ws + off); off += (size_t)NV * 64 * 2;
    u16* c1bf = (u16*)(ws + off); off += (size_t)NC * 64 * 2;
    u16* c2bf = (u16*)(ws + off); off += (size_t)NC * 64 * 2;
    float* agg_c = (float*)(ws + off); off += (size_t)NC * 64 * 4;
    float* agg_v = (float*)(ws + off); off += (size_t)NV * 64 * 4;
    u16* ev1s = (u16*)(ws + off); off += 2048 * 2;
    u16* ev2s = (u16*)(ws + off); off += 4096 * 2;
    u16* ec1s = (u16*)(ws + off); off += 2048 * 2;
    u16* ec2s = (u16*)(ws + off); off += 4096 * 2;
    u16* cg1s = (u16*)(ws + off); off += 10240 * 2;
    u16* cg2s = (u16*)(ws + off); off += 4096 * 2;
    u16* cf1s = (u16*)(ws + off); off += 8192 * 2;
    u16* cf2s = (u16*)(ws + off); off += 4096 * 2;
    u16* vg1s = (u16*)(ws + off); off += 10240 * 2;
    u16* vg2s = (u16*)(ws + off); off += 4096 * 2;
    u16* vf1s = (u16*)(ws + off); off += 8192 * 2;
    u16* vf2s = (u16*)(ws + off); off += 4096 * 2;
    u16* t1s  = (u16*)(ws + off); off += 4096 * 2;
    off = (off + 255) & ~(size_t)255;
    int* cnt    = (int*)(ws + off); off += (size_t)(NC + NV) * 4;
    int* done   = (int*)(ws + off); off += 4;          // contiguous after cnt
    off = (off + 255) & ~(size_t)255;
    int* basep  = (int*)(ws + off); off += (size_t)(NC + NV) * 4;
    int* bsum   = (int*)(ws + off); off += 64 * 4;
    off = (off + 255) & ~(size_t)255;
    u32* ranks  = (u32*)(ws + off); off += (size_t)NE * 4;
    off = (off + 255) & ~(size_t)255;
    int4* epk   = (int4*)(ws + off); off += (size_t)NE * 2 * 16;
    off = (off + 255) & ~(size_t)255;
    float* pu_c  = (float*)(ws + off); off += (size_t)NC * 64 * 4;
    float* pv_v  = (float*)(ws + off); off += (size_t)NV * 64 * 4;
    float* pu_v  = (float*)(ws + off); off += (size_t)NV * 64 * 4;
    float* pv_c2 = (float*)(ws + off); off += (size_t)NC * 64 * 4;

    const int n_tiles = NE / 64;
    const int nd = NC + NV;
    const int nb = (nd + SCAN_CHUNK - 1) / SCAN_CHUNK;
    const int nb_v = (NV + 63) / 64;
    const int nb_c = (NC + 63) / 64;

    hipMemsetAsync(cnt, 0, (size_t)nd * 4 + 4, stream);

    // 1) prep_weights || hist2
    prep_hist<<<552, 256, 0, stream>>>(
        ev_w1, ev_w2, ec_w1, ec_w2, cg_w1, cg_w2, cf_w1, cf_w2,
        vg_w1, vg_w2, vf_w1, vf_w2, t_w1,
        ev1s, ev2s, ec1s, ec2s, cg1s, cg2s, cf1s, cf2s,
        vg1s, vg2s, vf1s, vf2s, t1s,
        cons_idx, var_idx, NE, NC, cnt, (u32*)ranks);

    // 2) scan
    scan_part_bsum<<<nb, 256, 0, stream>>>(cnt, nd, bsum, nb, done);
    scan_final<<<nb, 256, 0, stream>>>(cnt, nd, bsum, basep);

    // 3) epk-scatter || mlp_in v (+Pu_v,+Pv_v) || mlp_in c (+Pu_c) || zero aggs
    mega<<<MEGA_SC + nb_v + nb_c + MEGA_ZB, 256, 0, stream>>>(
        cons_idx, var_idx, e_val, ranks, NE, NC, NV, basep, epk,
        v, ev1s, ev_b1, ev2s, ev_b2, v1bf,
        c, ec1s, ec_b1, ec2s, ec_b2, c1bf,
        cg1s, vg1s, pu_v, pv_v, pu_c,
        agg_c, agg_v);

    // 4) c-side conv (Pu_c + Pv_v) + f-MLP (also emits Pv_c2)
    edge_conv<<<1280, 256, 0, stream>>>(pu_c, pv_v, epk,
                                        cg_w1 + 128 * 64, cg_b1,
                                        cg2s, cg_b2, agg_c, n_tiles);
    node_mlp_f<<<nb_c, 256, 0, stream>>>(
        c1bf, agg_c, NC, cf1s, cf_b1, cf2s, cf_b2, vg1s, pv_c2, c2bf);

    // 5) v-side conv (Pu_v + Pv_c2) + f-MLP + tail
    edge_conv<<<1280, 256, 0, stream>>>(pu_v, pv_c2, epk + NE,
                                        vg_w1 + 128 * 64, vg_b1,
                                        vg2s, vg_b2, agg_v, n_tiles);
    node_mlp_vf_tail<<<nb_v, 256, 0, stream>>>(
        v1bf, agg_v, NV, vf1s, vf_b1, vf2s, vf_b2,
        t1s, t_b1, t_w2, t_b2, (float*)d_out);
}

// Round 10
// 445.061 us; speedup vs baseline: 1.1999x; 1.0874x over previous
//
#include <hip/hip_runtime.h>
#include <hip/hip_bf16.h>

typedef short short8 __attribute__((ext_vector_type(8)));
typedef float f32x4 __attribute__((ext_vector_type(4)));
typedef unsigned short u16;
typedef unsigned int u32;

__device__ __forceinline__ u16 bf16rne(float f) {
    u32 u = __float_as_uint(f);
    u32 r = (u + 0x7fffu + ((u >> 16) & 1u)) >> 16;
    return (u16)r;
}
__device__ __forceinline__ float bf2f(u16 s) {
    return __uint_as_float(((u32)s) << 16);
}

// LDS-only barrier: wave-sync + LDS visibility WITHOUT draining vmcnt.
__device__ __forceinline__ void ldsbar() {
    asm volatile("s_waitcnt lgkmcnt(0)" ::: "memory");
    __builtin_amdgcn_s_barrier();
    asm volatile("" ::: "memory");
}

// ---------------------------------------------------------------------------
// Weight swizzle into MFMA B-fragment order, bf16 (unchanged).
// ---------------------------------------------------------------------------
__device__ __forceinline__ void swz(const float* __restrict__ src,
                                    u16* __restrict__ dst, int K, int KT,
                                    int tid0, int stride) {
    int total = 4 * KT * 512;
    for (int i = tid0; i < total; i += stride) {
        int j = i & 7, lane = (i >> 3) & 63, g = i >> 9;
        int kt = g % KT;
        int k = kt * 32 + (lane >> 4) * 8 + j;
        int n = (g / KT) * 16 + (lane & 15);
        dst[i] = (k < K) ? bf16rne(src[k * 64 + n]) : (u16)0;
    }
}

// ---------------------------------------------------------------------------
// Fused prep_weights (blocks [0,40)) + hist2 (blocks [40,552)).
// ---------------------------------------------------------------------------
__global__ void prep_hist(
    const float* ev1, const float* ev2, const float* ec1, const float* ec2,
    const float* cg1, const float* cg2, const float* cf1, const float* cf2,
    const float* vg1, const float* vg2, const float* vf1, const float* vf2,
    const float* t1,
    u16* dev1, u16* dev2, u16* dec1, u16* dec2, u16* dcg1, u16* dcg2,
    u16* dcf1, u16* dcf2, u16* dvg1, u16* dvg2, u16* dvf1, u16* dvf2,
    u16* dt1,
    const int* __restrict__ ci, const int* __restrict__ vi, int ne, int nc,
    int* __restrict__ cnt, u32* __restrict__ ranks) {
    int b = blockIdx.x;
    if (b < 40) {
        int tid0 = b * blockDim.x + threadIdx.x;
        int st = 40 * blockDim.x;
        swz(ev1, dev1, 19, 1, tid0, st);
        swz(ev2, dev2, 64, 2, tid0, st);
        swz(ec1, dec1, 5, 1, tid0, st);
        swz(ec2, dec2, 64, 2, tid0, st);
        swz(cg1, dcg1, 129, 5, tid0, st);
        swz(cg2, dcg2, 64, 2, tid0, st);
        swz(cf1, dcf1, 128, 4, tid0, st);
        swz(cf2, dcf2, 64, 2, tid0, st);
        swz(vg1, dvg1, 129, 5, tid0, st);
        swz(vg2, dvg2, 64, 2, tid0, st);
        swz(vf1, dvf1, 128, 4, tid0, st);
        swz(vf2, dvf2, 64, 2, tid0, st);
        swz(t1, dt1, 64, 2, tid0, st);
    } else {
        int i = (b - 40) * blockDim.x + threadIdx.x;
        int st = 512 * blockDim.x;
        for (; i < ne; i += st) {
            int rc = atomicAdd(&cnt[ci[i]], 1);
            int rv = atomicAdd(&cnt[nc + vi[i]], 1);
            ranks[i] = ((u32)rc & 0xffffu) | ((u32)rv << 16);
        }
    }
}

// ---------------------------------------------------------------------------
// scan_part + last-block bsum scan (device-scope acquire/release).
// ---------------------------------------------------------------------------
#define SCAN_CHUNK 4096

__global__ void scan_part_bsum(const int* __restrict__ cnt, int nd,
                               int* __restrict__ bsum, int nb,
                               int* __restrict__ done) {
    __shared__ int sred[256];
    int b = blockIdx.x, t = threadIdx.x;
    int base = b * SCAN_CHUNK + t * 16;
    int s = 0;
#pragma unroll
    for (int j = 0; j < 16; j++) {
        int i = base + j;
        if (i < nd) s += cnt[i];
    }
    sred[t] = s;
    __syncthreads();
    for (int o = 128; o > 0; o >>= 1) {
        if (t < o) sred[t] += sred[t + o];
        __syncthreads();
    }
    if (t == 0) {
        __hip_atomic_store(&bsum[b], sred[0], __ATOMIC_RELEASE,
                           __HIP_MEMORY_SCOPE_AGENT);
        int prev = __hip_atomic_fetch_add(done, 1, __ATOMIC_ACQ_REL,
                                          __HIP_MEMORY_SCOPE_AGENT);
        if (prev == nb - 1) {
            int run = 0;
            for (int i = 0; i < nb; i++) {
                int vv = __hip_atomic_load(&bsum[i], __ATOMIC_ACQUIRE,
                                           __HIP_MEMORY_SCOPE_AGENT);
                __hip_atomic_store(&bsum[i], run, __ATOMIC_RELAXED,
                                   __HIP_MEMORY_SCOPE_AGENT);
                run += vv;
            }
        }
    }
}

__global__ void scan_final(const int* __restrict__ cnt, int nd,
                           const int* __restrict__ bsum,
                           int* __restrict__ basep) {
    __shared__ int sa[256];
    int b = blockIdx.x, t = threadIdx.x;
    int base = b * SCAN_CHUNK + t * 16;
    int loc[16];
    int s = 0;
#pragma unroll
    for (int j = 0; j < 16; j++) {
        int i = base + j;
        int v = (i < nd) ? cnt[i] : 0;
        loc[j] = s;
        s += v;
    }
    sa[t] = s;
    __syncthreads();
    int inc = s;
    for (int o = 1; o < 256; o <<= 1) {
        int v = (t >= o) ? sa[t - o] : 0;
        __syncthreads();
        sa[t] += v;
        __syncthreads();
    }
    int off = bsum[b] + sa[t] - inc;
#pragma unroll
    for (int j = 0; j < 16; j++) {
        int i = base + j;
        if (i < nd) basep[i] = off + loc[j];
    }
}

// ---------------------------------------------------------------------------
// Generic MFMA layer (bf16 out, unchanged).
// ---------------------------------------------------------------------------
template <int KT, int SA>
__device__ __forceinline__ void mfma_layer(const u16* __restrict__ Asrc,
                                           const short8* wf, float bv,
                                           u16* __restrict__ Hdst,
                                           int l15, int lq, int w) {
#pragma unroll
    for (int mt = 0; mt < 4; mt++) {
        f32x4 acc = {0.f, 0.f, 0.f, 0.f};
#pragma unroll
        for (int kt = 0; kt < KT; kt++) {
            short8 a = *(const short8*)(Asrc + (mt * 16 + l15) * SA + kt * 32 + lq * 8);
            acc = __builtin_amdgcn_mfma_f32_16x16x32_bf16(a, wf[kt], acc, 0, 0, 0);
        }
#pragma unroll
        for (int r = 0; r < 4; r++)
            Hdst[(mt * 16 + lq * 4 + r) * 72 + w * 16 + l15] =
                bf16rne(fmaxf(acc[r] + bv, 0.f));
    }
}

// ---------------------------------------------------------------------------
// Partial-product layers: A(bf16, stride 72) @ 2 fragments -> global
// [node][64]. No bias, no relu. f32 variant (Pu) and bf16 variant (Pv).
// ---------------------------------------------------------------------------
__device__ __forceinline__ void mfma_pout(const u16* __restrict__ Asrc,
                                          const short8* pf,
                                          float* __restrict__ outp,
                                          int blk0, int n_nodes,
                                          int l15, int lq, int w) {
#pragma unroll
    for (int mt = 0; mt < 4; mt++) {
        f32x4 acc = {0.f, 0.f, 0.f, 0.f};
#pragma unroll
        for (int kt = 0; kt < 2; kt++) {
            short8 a = *(const short8*)(Asrc + (mt * 16 + l15) * 72 + kt * 32 + lq * 8);
            acc = __builtin_amdgcn_mfma_f32_16x16x32_bf16(a, pf[kt], acc, 0, 0, 0);
        }
#pragma unroll
        for (int r = 0; r < 4; r++) {
            int gn = blk0 + mt * 16 + lq * 4 + r;
            if (gn < n_nodes)
                outp[(size_t)gn * 64 + w * 16 + l15] = acc[r];
        }
    }
}

__device__ __forceinline__ void mfma_pout_bf(const u16* __restrict__ Asrc,
                                             const short8* pf,
                                             u16* __restrict__ outp,
                                             int blk0, int n_nodes,
                                             int l15, int lq, int w) {
#pragma unroll
    for (int mt = 0; mt < 4; mt++) {
        f32x4 acc = {0.f, 0.f, 0.f, 0.f};
#pragma unroll
        for (int kt = 0; kt < 2; kt++) {
            short8 a = *(const short8*)(Asrc + (mt * 16 + l15) * 72 + kt * 32 + lq * 8);
            acc = __builtin_amdgcn_mfma_f32_16x16x32_bf16(a, pf[kt], acc, 0, 0, 0);
        }
#pragma unroll
        for (int r = 0; r < 4; r++) {
            int gn = blk0 + mt * 16 + lq * 4 + r;
            if (gn < n_nodes)
                outp[(size_t)gn * 64 + w * 16 + l15] = bf16rne(acc[r]);
        }
    }
}

// ---------------------------------------------------------------------------
// Input node MLP body + optional W1-partial outputs.
// paout: f32 (Pu, dst half); pbout: bf16 (Pv, src half).
// ---------------------------------------------------------------------------
template <int KIN>
__device__ __forceinline__ void mlp_in_body(
    const float* __restrict__ x, int n_nodes,
    const u16* __restrict__ w1s, const float* __restrict__ b1,
    const u16* __restrict__ w2s, const float* __restrict__ b2,
    u16* __restrict__ outbf, int blkid, u16* __restrict__ smem,
    const u16* __restrict__ paw, int pakt, float* __restrict__ paout,
    const u16* __restrict__ pbw, int pbkt, u16* __restrict__ pbout) {
    u16* A = smem;                 // 64*40
    u16* H1 = smem + 64 * 40;      // 64*72
    u16* H2 = H1 + 64 * 72;        // 64*72
    int tid = threadIdx.x, l = tid & 63, w = tid >> 6;
    int l15 = l & 15, lq = l >> 4;
    int blk0 = blkid * 64;
    const int PW = 40 - KIN;
    for (int i = tid; i < 64 * PW; i += 256) {
        int r = i / PW, cc = KIN + (i - r * PW);
        A[r * 40 + cc] = 0;
    }
    for (int i = tid; i < 64 * KIN; i += 256) {
        int r = i / KIN, k = i - r * KIN;
        int gn = blk0 + r; if (gn >= n_nodes) gn = n_nodes - 1;
        A[r * 40 + k] = bf16rne(x[(size_t)gn * KIN + k]);
    }
    short8 w1f[1], w2f[2];
    w1f[0] = *(const short8*)(w1s + ((w * 1 + 0) * 64 + l) * 8);
#pragma unroll
    for (int kt = 0; kt < 2; kt++)
        w2f[kt] = *(const short8*)(w2s + ((w * 2 + kt) * 64 + l) * 8);
    float b1v = b1[w * 16 + l15], b2v = b2[w * 16 + l15];
    ldsbar();
    mfma_layer<1, 40>(A, w1f, b1v, H1, l15, lq, w);
    ldsbar();
    mfma_layer<2, 72>(H1, w2f, b2v, H2, l15, lq, w);
    ldsbar();
    for (int i = tid; i < 512; i += 256) {
        int r = i >> 3, c = i & 7;
        if (blk0 + r < n_nodes)
            *(uint4*)(outbf + (size_t)(blk0 + r) * 64 + c * 8) =
                *(const uint4*)(H2 + r * 72 + c * 8);
    }
    if (paout) {
        short8 pf[2];
        pf[0] = *(const short8*)(paw + ((w * 5 + pakt + 0) * 64 + l) * 8);
        pf[1] = *(const short8*)(paw + ((w * 5 + pakt + 1) * 64 + l) * 8);
        mfma_pout(H2, pf, paout, blk0, n_nodes, l15, lq, w);
    }
    if (pbout) {
        short8 pf[2];
        pf[0] = *(const short8*)(pbw + ((w * 5 + pbkt + 0) * 64 + l) * 8);
        pf[1] = *(const short8*)(pbw + ((w * 5 + pbkt + 1) * 64 + l) * 8);
        mfma_pout_bf(H2, pf, pbout, blk0, n_nodes, l15, lq, w);
    }
}

// ---------------------------------------------------------------------------
// Mega kernel: epk-scatter (blocks [0,256), 4-way unrolled for ILP) ||
// mlp_in v (+Pu_v f32, +Pv_v bf16) || mlp_in c (+Pu_c f32) ||
// zero agg_c+agg_v.
// ---------------------------------------------------------------------------
#define MEGA_SC 256
#define MEGA_ZB 256

__global__ __launch_bounds__(256, 6) void mega(
    const int* __restrict__ ci, const int* __restrict__ vi,
    const float* __restrict__ ev, const u32* __restrict__ ranks,
    int ne, int nc, int nv, const int* __restrict__ basep,
    int4* __restrict__ epk,
    const float* __restrict__ vx, const u16* __restrict__ ev1s,
    const float* __restrict__ ev_b1, const u16* __restrict__ ev2s,
    const float* __restrict__ ev_b2, u16* __restrict__ v1bf,
    const float* __restrict__ cx, const u16* __restrict__ ec1s,
    const float* __restrict__ ec_b1, const u16* __restrict__ ec2s,
    const float* __restrict__ ec_b2, u16* __restrict__ c1bf,
    const u16* __restrict__ cg1s, const u16* __restrict__ vg1s,
    float* __restrict__ pu_v, u16* __restrict__ pv_v,
    float* __restrict__ pu_c,
    float* __restrict__ agg_c, float* __restrict__ agg_v) {
    __shared__ __align__(16) u16 smem[64 * 40 + 2 * 64 * 72];
    int b = blockIdx.x;
    int nb_v = (nv + 63) >> 6;
    int nb_c = (nc + 63) >> 6;
    if (b < MEGA_SC) {
        int i = b * 256 + threadIdx.x;
        const int st = MEGA_SC * 256;
        // 4-deep unrolled grid-stride: 4 independent load->store chains
        while (i + 3 * st < ne) {
            int i1 = i + st, i2 = i + 2 * st, i3 = i + 3 * st;
            int cd0 = ci[i],  cd1 = ci[i1], cd2 = ci[i2], cd3 = ci[i3];
            int vd0 = vi[i],  vd1 = vi[i1], vd2 = vi[i2], vd3 = vi[i3];
            u32 rk0 = ranks[i],  rk1 = ranks[i1];
            u32 rk2 = ranks[i2], rk3 = ranks[i3];
            int eb0 = __float_as_int(ev[i]),  eb1 = __float_as_int(ev[i1]);
            int eb2 = __float_as_int(ev[i2]), eb3 = __float_as_int(ev[i3]);
            int pc0 = basep[cd0] + (int)(rk0 & 0xffffu);
            int pc1 = basep[cd1] + (int)(rk1 & 0xffffu);
            int pc2 = basep[cd2] + (int)(rk2 & 0xffffu);
            int pc3 = basep[cd3] + (int)(rk3 & 0xffffu);
            int pv0 = basep[nc + vd0] + (int)(rk0 >> 16);
            int pv1 = basep[nc + vd1] + (int)(rk1 >> 16);
            int pv2 = basep[nc + vd2] + (int)(rk2 >> 16);
            int pv3 = basep[nc + vd3] + (int)(rk3 >> 16);
            epk[pc0] = make_int4(cd0, vd0, eb0, 0);
            epk[pc1] = make_int4(cd1, vd1, eb1, 0);
            epk[pc2] = make_int4(cd2, vd2, eb2, 0);
            epk[pc3] = make_int4(cd3, vd3, eb3, 0);
            epk[pv0] = make_int4(vd0, cd0, eb0, 0);
            epk[pv1] = make_int4(vd1, cd1, eb1, 0);
            epk[pv2] = make_int4(vd2, cd2, eb2, 0);
            epk[pv3] = make_int4(vd3, cd3, eb3, 0);
            i += 4 * st;
        }
        for (; i < ne; i += st) {
            int cd = ci[i], vd = vi[i];
            u32 rk = ranks[i];
            int eb = __float_as_int(ev[i]);
            int pc = basep[cd] + (int)(rk & 0xffffu);
            int pv = basep[nc + vd] + (int)(rk >> 16);
            epk[pc] = make_int4(cd, vd, eb, 0);
            epk[pv] = make_int4(vd, cd, eb, 0);
        }
    } else if (b < MEGA_SC + nb_v) {
        // v1 + Pu_v (vg dst half, kt 0) + Pv_v (cg src half, kt 2)
        mlp_in_body<19>(vx, nv, ev1s, ev_b1, ev2s, ev_b2, v1bf, b - MEGA_SC,
                        smem, vg1s, 0, pu_v, cg1s, 2, pv_v);
    } else if (b < MEGA_SC + nb_v + nb_c) {
        // c1 + Pu_c (cg dst half, kt 0)
        mlp_in_body<5>(cx, nc, ec1s, ec_b1, ec2s, ec_b2, c1bf,
                       b - MEGA_SC - nb_v, smem, cg1s, 0, pu_c,
                       (const u16*)0, 0, (u16*)0);
    } else {
        int zb = b - MEGA_SC - nb_v - nb_c;          // 0..MEGA_ZB-1
        size_t nct = (size_t)nc * 64;
        size_t total = nct + (size_t)nv * 64;
        float4 z = {0.f, 0.f, 0.f, 0.f};
        size_t i = ((size_t)zb * 256 + threadIdx.x) * 4;
        size_t stp = (size_t)MEGA_ZB * 256 * 4;
        for (; i < total; i += stp) {
            if (i < nct) *(float4*)(agg_c + i) = z;
            else         *(float4*)(agg_v + (i - nct)) = z;
        }
    }
}

// ---------------------------------------------------------------------------
// f-MLP staging (unchanged).
// ---------------------------------------------------------------------------
__device__ __forceinline__ void stage_concat_res(
    const u16* __restrict__ ubf, const float* __restrict__ agg,
    int blk0, int n_nodes, u16* __restrict__ A, int tid) {
    for (int i = tid; i < 64 * 24; i += 256) {
        int nd = i / 24, c = i - nd * 24;
        int gn = blk0 + nd; if (gn >= n_nodes) gn = n_nodes - 1;
        if (c < 8) {
            *(uint4*)(A + nd * 200 + c * 8) =
                *(const uint4*)(ubf + (size_t)gn * 64 + c * 8);
        } else {
            int q = c - 8;
            float4 av = *(const float4*)(agg + (size_t)gn * 64 + q * 4);
            u16 h0 = bf16rne(av.x), h1 = bf16rne(av.y);
            u16 h2 = bf16rne(av.z), h3 = bf16rne(av.w);
            uint2 hi;
            hi.x = (u32)h0 | ((u32)h1 << 16);
            hi.y = (u32)h2 | ((u32)h3 << 16);
            *(uint2*)(A + nd * 200 + 64 + q * 4) = hi;
            uint2 rs;
            rs.x = (u32)bf16rne(av.x - bf2f(h0)) | ((u32)bf16rne(av.y - bf2f(h1)) << 16);
            rs.y = (u32)bf16rne(av.z - bf2f(h2)) | ((u32)bf16rne(av.w - bf2f(h3)) << 16);
            *(uint2*)(A + nd * 200 + 128 + q * 4) = rs;
        }
    }
}

// ---------------------------------------------------------------------------
// c-side f-MLP + Pv_c2 output (vg src half, kt 2; bf16) for the v-side conv.
// ---------------------------------------------------------------------------
__global__ __launch_bounds__(256, 4) void node_mlp_f(
    const u16* __restrict__ ubf, const float* __restrict__ agg, int n_nodes,
    const u16* __restrict__ w1s, const float* __restrict__ b1,
    const u16* __restrict__ w2s, const float* __restrict__ b2,
    const u16* __restrict__ vg1s, u16* __restrict__ pv_out,
    u16* __restrict__ outbf) {
    __shared__ __align__(16) u16 A[64 * 200];
    __shared__ __align__(16) u16 H1[64 * 72];
    int tid = threadIdx.x, l = tid & 63, w = tid >> 6;
    int l15 = l & 15, lq = l >> 4;
    int blk0 = blockIdx.x * 64;
    stage_concat_res(ubf, agg, blk0, n_nodes, A, tid);
    short8 w1f[6], w2f[2];
#pragma unroll
    for (int kt = 0; kt < 4; kt++)
        w1f[kt] = *(const short8*)(w1s + ((w * 4 + kt) * 64 + l) * 8);
    w1f[4] = w1f[2];
    w1f[5] = w1f[3];
#pragma unroll
    for (int kt = 0; kt < 2; kt++)
        w2f[kt] = *(const short8*)(w2s + ((w * 2 + kt) * 64 + l) * 8);
    float b1v = b1[w * 16 + l15], b2v = b2[w * 16 + l15];
    ldsbar();
    mfma_layer<6, 200>(A, w1f, b1v, H1, l15, lq, w);
    ldsbar();
    mfma_layer<2, 72>(H1, w2f, b2v, A, l15, lq, w);   // A region dead: reuse (c2)
    ldsbar();
    for (int i = tid; i < 512; i += 256) {
        int r = i >> 3, c = i & 7;
        if (blk0 + r < n_nodes)
            *(uint4*)(outbf + (size_t)(blk0 + r) * 64 + c * 8) =
                *(const uint4*)(A + r * 72 + c * 8);
    }
    {
        short8 pf[2];
        pf[0] = *(const short8*)(vg1s + ((w * 5 + 2) * 64 + l) * 8);
        pf[1] = *(const short8*)(vg1s + ((w * 5 + 3) * 64 + l) * 8);
        mfma_pout_bf(A, pf, pv_out, blk0, n_nodes, l15, lq, w);
    }
}

// ---------------------------------------------------------------------------
// v-side f-MLP + tail (unchanged).
// ---------------------------------------------------------------------------
__global__ __launch_bounds__(256, 3) void node_mlp_vf_tail(
    const u16* __restrict__ vbf, const float* __restrict__ agg, int n_nodes,
    const u16* __restrict__ w1s, const float* __restrict__ b1,
    const u16* __restrict__ w2s, const float* __restrict__ b2,
    const u16* __restrict__ t1s, const float* __restrict__ tb1,
    const float* __restrict__ tw2, const float* __restrict__ tb2,
    float* __restrict__ out) {
    __shared__ __align__(16) char smem[64 * 200 * 2 + 2 * 64 * 72 * 2];
    u16* A = (u16*)smem;
    float* XF = (float*)smem;
    u16* H1 = (u16*)(smem + 25600);
    u16* H2 = (u16*)(smem + 25600 + 9216);
    int tid = threadIdx.x, l = tid & 63, w = tid >> 6;
    int l15 = l & 15, lq = l >> 4;
    int blk0 = blockIdx.x * 64;
    stage_concat_res(vbf, agg, blk0, n_nodes, A, tid);
    short8 w1f[6], w2f[2], t1f[2];
#pragma unroll
    for (int kt = 0; kt < 4; kt++)
        w1f[kt] = *(const short8*)(w1s + ((w * 4 + kt) * 64 + l) * 8);
    w1f[4] = w1f[2];
    w1f[5] = w1f[3];
#pragma unroll
    for (int kt = 0; kt < 2; kt++) {
        w2f[kt] = *(const short8*)(w2s + ((w * 2 + kt) * 64 + l) * 8);
        t1f[kt] = *(const short8*)(t1s + ((w * 2 + kt) * 64 + l) * 8);
    }
    float b1v = b1[w * 16 + l15], b2v = b2[w * 16 + l15];
    float tb1v = tb1[w * 16 + l15];
    ldsbar();
    mfma_layer<6, 200>(A, w1f, b1v, H1, l15, lq, w);
    ldsbar();
    mfma_layer<2, 72>(H1, w2f, b2v, H2, l15, lq, w);
    ldsbar();
#pragma unroll
    for (int mt = 0; mt < 4; mt++) {
        f32x4 acc = {0.f, 0.f, 0.f, 0.f};
#pragma unroll
        for (int kt = 0; kt < 2; kt++) {
            short8 a = *(const short8*)(H2 + (mt * 16 + l15) * 72 + kt * 32 + lq * 8);
            acc = __builtin_amdgcn_mfma_f32_16x16x32_bf16(a, t1f[kt], acc, 0, 0, 0);
        }
#pragma unroll
        for (int r = 0; r < 4; r++)
            XF[(mt * 16 + lq * 4 + r) * 65 + w * 16 + l15] =
                fmaxf(acc[r] + tb1v, 0.f);
    }
    ldsbar();
    float s0 = tb2[2 * w], s1 = tb2[2 * w + 1];
    for (int k = 0; k < 64; k++) {
        float xk = XF[l * 65 + k];
        float2 wp = *(const float2*)(tw2 + k * 8 + 2 * w);
        s0 = fmaf(xk, wp.x, s0);
        s1 = fmaf(xk, wp.y, s1);
    }
    if (blk0 + l < n_nodes) {
        float2 r;
        r.x = 1.f / (1.f + __expf(-s0));
        r.y = 1.f / (1.f + __expf(-s1));
        *(float2*)(out + (size_t)(blk0 + l) * 8 + 2 * w) = r;
    }
}

// ---------------------------------------------------------------------------
// Edge conv, R10: W1-linearity decomposition (R9 structure). Pv is now
// bf16 (halves the random-gather bytes); occupancy 5 -> 6 blocks/CU.
// Per edge: h1 = relu(Pu[dst](f32) + Pv[src](bf16) + e*w1e + b1) (VALU)
// -> bf16 Hs -> B1 -> L2 MFMA -> Gf -> B2 -> seg-reduce. 2 barriers/tile.
// LDS = 9216(Hs) + 16896(Gf) + 512(Didx[2]) = 26624 B -> 6 blocks/CU.
// ---------------------------------------------------------------------------
#define HROW 72
#define GST 66

__global__ __launch_bounds__(256, 6) void edge_conv(
    const float* __restrict__ Pu,   // [ndst][64] f32 W1-dst partial
    const u16* __restrict__ Pv,     // [nsrc][64] bf16 W1-src partial
    const int4* __restrict__ epk,   // sorted packed edges {dst, src, ev, 0}
    const float* __restrict__ w1e,  // W1 row 128 (e column), 64 f32
    const float* __restrict__ b1,
    const u16* __restrict__ w2s, const float* __restrict__ b2,
    float* __restrict__ agg, int n_tiles) {
    __shared__ __align__(16) u16 Hs[64 * HROW];
    __shared__ __align__(16) float Gf[64 * GST];
    __shared__ int Didx[2][64];

    int tid = threadIdx.x;
    int lane = tid & 63;
    int w = tid >> 6;
    int l15 = lane & 15, lq = lane >> 4;
    int cch = tid & 15, e0 = tid >> 4;   // thread: edges e0+16t, cols cch*4..+4

    short8 w2f[2];
#pragma unroll
    for (int kt = 0; kt < 2; kt++)
        w2f[kt] = *(const short8*)(w2s + ((w * 2 + kt) * 64 + lane) * 8);
    float b2v = b2[w * 16 + l15];
    float4 w1e4 = *(const float4*)(w1e + cch * 4);
    float4 b14  = *(const float4*)(b1 + cch * 4);

    const int* epki = (const int*)epk;
    const int G = gridDim.x;
    int tile = (int)blockIdx.x;

    uint2 pvu[4];          // Pv bf16x4 gather, current tile (1 ahead)
    u32 evc[4];            // e_val bits, current tile
    int dstc[4];           // dst ids, current tile
    int ndst[4], nsrc[4];  // epk fields for NEXT tile (2 ahead)
    u32 nev[4];
    int didx_c = 0, didx_n = 0;
    int par = 0;

    if (tile < n_tiles) {
#pragma unroll
        for (int t = 0; t < 4; t++) {
            int4 e = epk[tile * 64 + e0 + t * 16];
            pvu[t] = *(const uint2*)(Pv + (size_t)e.y * 64 + cch * 4);
            evc[t] = (u32)e.z;
            dstc[t] = e.x;
        }
        if (tid < 64) didx_c = epki[(tile * 64 + tid) * 4];
        int ntp = tile + G;
        if (ntp < n_tiles) {
#pragma unroll
            for (int t = 0; t < 4; t++) {
                int4 e = epk[ntp * 64 + e0 + t * 16];
                ndst[t] = e.x; nsrc[t] = e.y; nev[t] = (u32)e.z;
            }
        }
    }

    for (; tile < n_tiles; tile += G) {
        // stage Hs: h1 = relu(Pu[dst] + Pv[src] + e*w1e + b1) -> bf16
#pragma unroll
        for (int t = 0; t < 4; t++) {
            int e = e0 + t * 16;
            f32x4 pu4 = *(const f32x4*)(Pu + (size_t)dstc[t] * 64 + cch * 4);
            float pv0 = bf2f((u16)(pvu[t].x & 0xffffu));
            float pv1 = bf2f((u16)(pvu[t].x >> 16));
            float pv2 = bf2f((u16)(pvu[t].y & 0xffffu));
            float pv3 = bf2f((u16)(pvu[t].y >> 16));
            float ev = __uint_as_float(evc[t]);
            float h0 = fmaxf(pv0 + pu4[0] + ev * w1e4.x + b14.x, 0.f);
            float h1 = fmaxf(pv1 + pu4[1] + ev * w1e4.y + b14.y, 0.f);
            float h2 = fmaxf(pv2 + pu4[2] + ev * w1e4.z + b14.z, 0.f);
            float h3 = fmaxf(pv3 + pu4[3] + ev * w1e4.w + b14.w, 0.f);
            uint2 pk;
            pk.x = (u32)bf16rne(h0) | ((u32)bf16rne(h1) << 16);
            pk.y = (u32)bf16rne(h2) | ((u32)bf16rne(h3) << 16);
            *(uint2*)(&Hs[e * HROW + cch * 4]) = pk;
        }
        if (tid < 64) Didx[par][tid] = didx_c;
        // pipeline: gather next tile's Pv (indices in regs), prefetch tile+2
        int nt = tile + G;
        if (nt < n_tiles) {
#pragma unroll
            for (int t = 0; t < 4; t++) {
                pvu[t] = *(const uint2*)(Pv + (size_t)nsrc[t] * 64 + cch * 4);
                evc[t] = nev[t];
                dstc[t] = ndst[t];
            }
            if (tid < 64) didx_n = epki[(nt * 64 + tid) * 4];
            int nt2 = nt + G;
            if (nt2 < n_tiles) {
#pragma unroll
                for (int t = 0; t < 4; t++) {
                    int4 e = epk[nt2 * 64 + e0 + t * 16];
                    ndst[t] = e.x; nsrc[t] = e.y; nev[t] = (u32)e.z;
                }
            }
        }
        ldsbar();  // B1: Hs + Didx[par] ready; prev seg-reduce Gf reads done

        // L2 MFMA -> Gf (f32, stride 66)
#pragma unroll
        for (int mt = 0; mt < 4; mt++) {
            short8 a2[2];
#pragma unroll
            for (int kt = 0; kt < 2; kt++)
                a2[kt] = *(const short8*)(&Hs[(mt * 16 + l15) * HROW + kt * 32 + lq * 8]);
            f32x4 acc = {0.f, 0.f, 0.f, 0.f};
#pragma unroll
            for (int kt = 0; kt < 2; kt++)
                acc = __builtin_amdgcn_mfma_f32_16x16x32_bf16(a2[kt], w2f[kt], acc, 0, 0, 0);
#pragma unroll
            for (int r = 0; r < 4; r++)
                Gf[(mt * 16 + lq * 4 + r) * GST + w * 16 + l15] =
                    fmaxf(acc[r] + b2v, 0.f);
        }
        ldsbar();  // B2: Gf ready

        // segmented reduce: thread t scans 16 rows of col t&63
        {
            int col = tid & 63, rg = tid >> 6;
            int r0 = rg * 16;
            int dcur = Didx[par][r0];
            float s = Gf[r0 * GST + col];
#pragma unroll
            for (int r = 1; r < 16; r++) {
                int d = Didx[par][r0 + r];
                float g = Gf[(r0 + r) * GST + col];
                if (d != dcur) {
                    __hip_atomic_fetch_add(&agg[(size_t)dcur * 64 + col], s,
                                           __ATOMIC_RELAXED, __HIP_MEMORY_SCOPE_AGENT);
                    dcur = d;
                    s = g;
                } else {
                    s += g;
                }
            }
            __hip_atomic_fetch_add(&agg[(size_t)dcur * 64 + col], s,
                                   __ATOMIC_RELAXED, __HIP_MEMORY_SCOPE_AGENT);
        }
        didx_c = didx_n;
        par ^= 1;
    }
}

extern "C" void kernel_launch(void* const* d_in, const int* in_sizes, int n_in,
                              void* d_out, int out_size, void* d_ws, size_t ws_size,
                              hipStream_t stream) {
    const float* v        = (const float*)d_in[0];
    const float* c        = (const float*)d_in[1];
    const int*   cons_idx = (const int*)d_in[2];
    const int*   var_idx  = (const int*)d_in[3];
    const float* e_val    = (const float*)d_in[4];
    const float* ev_w1 = (const float*)d_in[5],  *ev_b1 = (const float*)d_in[6];
    const float* ev_w2 = (const float*)d_in[7],  *ev_b2 = (const float*)d_in[8];
    const float* ec_w1 = (const float*)d_in[9],  *ec_b1 = (const float*)d_in[10];
    const float* ec_w2 = (const float*)d_in[11], *ec_b2 = (const float*)d_in[12];
    const float* cg_w1 = (const float*)d_in[13], *cg_b1 = (const float*)d_in[14];
    const float* cg_w2 = (const float*)d_in[15], *cg_b2 = (const float*)d_in[16];
    const float* cf_w1 = (const float*)d_in[17], *cf_b1 = (const float*)d_in[18];
    const float* cf_w2 = (const float*)d_in[19], *cf_b2 = (const float*)d_in[20];
    const float* vg_w1 = (const float*)d_in[21], *vg_b1 = (const float*)d_in[22];
    const float* vg_w2 = (const float*)d_in[23], *vg_b2 = (const float*)d_in[24];
    const float* vf_w1 = (const float*)d_in[25], *vf_b1 = (const float*)d_in[26];
    const float* vf_w2 = (const float*)d_in[27], *vf_b2 = (const float*)d_in[28];
    const float* t_w1  = (const float*)d_in[29], *t_b1  = (const float*)d_in[30];
    const float* t_w2  = (const float*)d_in[31], *t_b2  = (const float*)d_in[32];

    const int NV = in_sizes[0] / 19;
    const int NC = in_sizes[1] / 5;
    const int NE = in_sizes[4];

    char* ws = (char*)d_ws;
    size_t off = 0;
    u16* v1bf = (u16*)(ws + off); off += (size_t)NV * 64 * 2;
    u16* c1bf = (u16*)(ws + off); off += (size_t)NC * 64 * 2;
    u16* c2bf = (u16*)(ws + off); off += (size_t)NC * 64 * 2;
    float* agg_c = (float*)(ws + off); off += (size_t)NC * 64 * 4;
    float* agg_v = (float*)(ws + off); off += (size_t)NV * 64 * 4;
    u16* ev1s = (u16*)(ws + off); off += 2048 * 2;
    u16* ev2s = (u16*)(ws + off); off += 4096 * 2;
    u16* ec1s = (u16*)(ws + off); off += 2048 * 2;
    u16* ec2s = (u16*)(ws + off); off += 4096 * 2;
    u16* cg1s = (u16*)(ws + off); off += 10240 * 2;
    u16* cg2s = (u16*)(ws + off); off += 4096 * 2;
    u16* cf1s = (u16*)(ws + off); off += 8192 * 2;
    u16* cf2s = (u16*)(ws + off); off += 4096 * 2;
    u16* vg1s = (u16*)(ws + off); off += 10240 * 2;
    u16* vg2s = (u16*)(ws + off); off += 4096 * 2;
    u16* vf1s = (u16*)(ws + off); off += 8192 * 2;
    u16* vf2s = (u16*)(ws + off); off += 4096 * 2;
    u16* t1s  = (u16*)(ws + off); off += 4096 * 2;
    off = (off + 255) & ~(size_t)255;
    int* cnt    = (int*)(ws + off); off += (size_t)(NC + NV) * 4;
    int* done   = (int*)(ws + off); off += 4;          // contiguous after cnt
    off = (off + 255) & ~(size_t)255;
    int* basep  = (int*)(ws + off); off += (size_t)(NC + NV) * 4;
    int* bsum   = (int*)(ws + off); off += 64 * 4;
    off = (off + 255) & ~(size_t)255;
    u32* ranks  = (u32*)(ws + off); off += (size_t)NE * 4;
    off = (off + 255) & ~(size_t)255;
    int4* epk   = (int4*)(ws + off); off += (size_t)NE * 2 * 16;
    off = (off + 255) & ~(size_t)255;
    float* pu_c  = (float*)(ws + off); off += (size_t)NC * 64 * 4;
    float* pu_v  = (float*)(ws + off); off += (size_t)NV * 64 * 4;
    u16* pv_v    = (u16*)(ws + off);   off += (size_t)NV * 64 * 2;
    u16* pv_c2   = (u16*)(ws + off);   off += (size_t)NC * 64 * 2;

    const int n_tiles = NE / 64;
    const int nd = NC + NV;
    const int nb = (nd + SCAN_CHUNK - 1) / SCAN_CHUNK;
    const int nb_v = (NV + 63) / 64;
    const int nb_c = (NC + 63) / 64;

    hipMemsetAsync(cnt, 0, (size_t)nd * 4 + 4, stream);

    // 1) prep_weights || hist2
    prep_hist<<<552, 256, 0, stream>>>(
        ev_w1, ev_w2, ec_w1, ec_w2, cg_w1, cg_w2, cf_w1, cf_w2,
        vg_w1, vg_w2, vf_w1, vf_w2, t_w1,
        ev1s, ev2s, ec1s, ec2s, cg1s, cg2s, cf1s, cf2s,
        vg1s, vg2s, vf1s, vf2s, t1s,
        cons_idx, var_idx, NE, NC, cnt, (u32*)ranks);

    // 2) scan
    scan_part_bsum<<<nb, 256, 0, stream>>>(cnt, nd, bsum, nb, done);
    scan_final<<<nb, 256, 0, stream>>>(cnt, nd, bsum, basep);

    // 3) epk-scatter || mlp_in v (+Pu_v,+Pv_v) || mlp_in c (+Pu_c) || zero aggs
    mega<<<MEGA_SC + nb_v + nb_c + MEGA_ZB, 256, 0, stream>>>(
        cons_idx, var_idx, e_val, ranks, NE, NC, NV, basep, epk,
        v, ev1s, ev_b1, ev2s, ev_b2, v1bf,
        c, ec1s, ec_b1, ec2s, ec_b2, c1bf,
        cg1s, vg1s, pu_v, pv_v, pu_c,
        agg_c, agg_v);

    // 4) c-side conv (Pu_c + Pv_v) + f-MLP (also emits Pv_c2)
    edge_conv<<<1536, 256, 0, stream>>>(pu_c, pv_v, epk,
                                        cg_w1 + 128 * 64, cg_b1,
                                        cg2s, cg_b2, agg_c, n_tiles);
    node_mlp_f<<<nb_c, 256, 0, stream>>>(
        c1bf, agg_c, NC, cf1s, cf_b1, cf2s, cf_b2, vg1s, pv_c2, c2bf);

    // 5) v-side conv (Pu_v + Pv_c2) + f-MLP + tail
    edge_conv<<<1536, 256, 0, stream>>>(pu_v, pv_c2, epk + NE,
                                        vg_w1 + 128 * 64, vg_b1,
                                        vg2s, vg_b2, agg_v, n_tiles);
    node_mlp_vf_tail<<<nb_v, 256, 0, stream>>>(
        v1bf, agg_v, NV, vf1s, vf_b1, vf2s, vf_b2,
        t1s, t_b1, t_w2, t_b2, (float*)d_out);
}